// Round 1
// baseline (908.023 us; speedup 1.0000x reference)
//
#include <hip/hip_runtime.h>
#include <hip/hip_bf16.h>

// Problem constants
#define NSEQ 4096
#define C4   1024
#define SCALE_F 0.17677669529663687f   // (256/8)^-0.5

typedef __attribute__((ext_vector_type(8))) short bf16x8;
typedef __attribute__((ext_vector_type(4))) float f32x4;
typedef __attribute__((ext_vector_type(8))) unsigned short u16x8;
typedef __attribute__((ext_vector_type(4))) unsigned short u16x4;

__device__ __forceinline__ float b2f(unsigned short b){
  union{unsigned u; float f;} v; v.u = ((unsigned)b)<<16; return v.f;
}
__device__ __forceinline__ unsigned short f2b(float x){
  union{float f; unsigned u;} v; v.f = x;
  unsigned r = v.u + 0x7fffu + ((v.u>>16)&1u);
  return (unsigned short)(r>>16);
}

typedef __attribute__((address_space(1))) void* gas_p;
typedef __attribute__((address_space(3))) void* las_p;
#define GLDS16(gp, lp) __builtin_amdgcn_global_load_lds((gas_p)(gp), (las_p)(lp), 16, 0, 0)

// Stage a 128x64 bf16 tile from row-major global (leading dim ld) into linear LDS [128][64].
__device__ __forceinline__ void stage128x64(const unsigned short* G, int row0, int ld, int k0,
                                            unsigned short* lds, int tid){
#pragma unroll
  for (int i = 0; i < 4; ++i){
    int cid = i*256 + tid;          // 1024 chunks of 16B
    int r = cid >> 3, c8 = cid & 7;
    GLDS16(G + (row0 + r)*ld + k0 + c8*8, lds + cid*8);
  }
}

// MFMA over staged tiles. ldsA/ldsB row-major [128][LD] bf16, NK = LD/32 k-chunks.
// Computes D[m,n] += sum_k A[m,k]*B[n,k]  (both operands reduction-contiguous).
template<int LD, int NK>
__device__ __forceinline__ void mma_tiles(const unsigned short* ldsA, const unsigned short* ldsB,
                                          f32x4 acc[4][4], int wr, int wc, int lane){
  const int rowg = lane & 15, kg = (lane >> 4) * 8;
#pragma unroll
  for (int kc = 0; kc < NK; ++kc){
    bf16x8 a[4], b[4];
#pragma unroll
    for (int mf = 0; mf < 4; ++mf)
      a[mf] = *(const bf16x8*)(ldsA + (wr*64 + mf*16 + rowg)*LD + kc*32 + kg);
#pragma unroll
    for (int nf = 0; nf < 4; ++nf)
      b[nf] = *(const bf16x8*)(ldsB + (wc*64 + nf*16 + rowg)*LD + kc*32 + kg);
#pragma unroll
    for (int mf = 0; mf < 4; ++mf)
#pragma unroll
      for (int nf = 0; nf < 4; ++nf)
        acc[mf][nf] = __builtin_amdgcn_mfma_f32_16x16x32_bf16(a[mf], b[nf], acc[mf][nf], 0, 0, 0);
  }
}

// ---------------- casts ----------------
__global__ __launch_bounds__(256) void k_cast(const float* __restrict__ src,
                                              unsigned short* __restrict__ dst, int n){
  int i = (blockIdx.x*256 + threadIdx.x) * 4;
  if (i < n){
    float4 v = *(const float4*)(src + i);
    u16x4 o = { f2b(v.x), f2b(v.y), f2b(v.z), f2b(v.w) };
    *(u16x4*)(dst + i) = o;
  }
}

// WvT[j][c4] = Wv[c4][j], bf16.  Wv: [1024][256] f32.
__global__ __launch_bounds__(256) void k_transpose_wv(const float* __restrict__ Wv,
                                                      unsigned short* __restrict__ WvT){
  int t = blockIdx.x*256 + threadIdx.x;      // 262144 threads
  int j = t & 255, r = t >> 8;
  WvT[j*C4 + r] = f2b(Wv[r*256 + j]);
}

// ---------------- q/k projection: C[m,j] = sum_k x[m,k] * Wcat[j,k] ----------------
__global__ __launch_bounds__(256) void k_gemm_qk(const unsigned short* __restrict__ xbf,
                                                 const unsigned short* __restrict__ Wcat,
                                                 unsigned short* __restrict__ Xq,
                                                 unsigned short* __restrict__ Xk){
  __shared__ __align__(16) unsigned short ldsA[128*64];
  __shared__ __align__(16) unsigned short ldsB[128*64];
  int tid = threadIdx.x, lane = tid & 63, wid = tid >> 6, wr = wid >> 1, wc = wid & 1;
  int m0 = blockIdx.x*128, n0 = blockIdx.y*128;
  f32x4 acc[4][4] = {};
  for (int k0 = 0; k0 < 256; k0 += 64){
    __syncthreads();
    stage128x64(xbf,  m0, 256, k0, ldsA, tid);
    stage128x64(Wcat, n0, 256, k0, ldsB, tid);
    __syncthreads();
    mma_tiles<64,2>(ldsA, ldsB, acc, wr, wc, lane);
  }
  int colg = lane & 15, rowg = (lane >> 4) * 4;
#pragma unroll
  for (int mf = 0; mf < 4; ++mf)
#pragma unroll
    for (int nf = 0; nf < 4; ++nf){
      int col = n0 + wc*64 + nf*16 + colg;
      unsigned short* dst = (col < 1024) ? Xq : Xk;
      int c4 = col & 1023;
#pragma unroll
      for (int r = 0; r < 4; ++r){
        int row = m0 + wr*64 + mf*16 + rowg + r;
        dst[row*C4 + c4] = f2b(acc[mf][nf][r]);
      }
    }
}

// ---------------- adaptive max pool: basesRaw[sb][k][c] = max over 32-window ----------------
__global__ __launch_bounds__(256) void k_pool(const unsigned short* __restrict__ Xq,
                                              const unsigned short* __restrict__ Xk,
                                              float* __restrict__ basesRaw){
  int k = blockIdx.x, sb = blockIdx.y, tid = threadIdx.x;
  const unsigned short* Xsb = ((sb >= 8) ? Xk : Xq) + (sb & 7) * (NSEQ*C4);
  int c0 = tid * 4;
  float m0 = -3e38f, m1 = -3e38f, m2 = -3e38f, m3 = -3e38f;
  for (int nn = 0; nn < 32; ++nn){
    u16x4 v = *(const u16x4*)(Xsb + (k*32 + nn)*C4 + c0);
    m0 = fmaxf(m0, b2f(v[0])); m1 = fmaxf(m1, b2f(v[1]));
    m2 = fmaxf(m2, b2f(v[2])); m3 = fmaxf(m3, b2f(v[3]));
  }
  float4 o = { m0, m1, m2, m3 };
  *(float4*)(basesRaw + (sb*128 + k)*C4 + c0) = o;
}

// ---------------- l2-normalize rows of basesRaw over c -> basesT bf16 ----------------
__global__ __launch_bounds__(256) void k_norm(const float* __restrict__ basesRaw,
                                              unsigned short* __restrict__ basesT){
  int row = blockIdx.x, tid = threadIdx.x, lane = tid & 63, wid = tid >> 6;
  const float* src = basesRaw + row*C4;
  float4 v = *(const float4*)(src + tid*4);
  float ss = v.x*v.x + v.y*v.y + v.z*v.z + v.w*v.w;
  __shared__ float red[5];
#pragma unroll
  for (int o = 32; o; o >>= 1) ss += __shfl_down(ss, o);
  if (lane == 0) red[wid] = ss;
  __syncthreads();
  if (tid == 0) red[4] = 1.f / (1e-6f + sqrtf(red[0] + red[1] + red[2] + red[3]));
  __syncthreads();
  float inv = red[4];
  u16x4 o4 = { f2b(v.x*inv), f2b(v.y*inv), f2b(v.z*inv), f2b(v.w*inv) };
  *(u16x4*)(basesT + row*C4 + tid*4) = o4;
}

// ---------------- z-step: scores[n,k] = X[n,:].basesT[k,:]; softmax over k; store zT[k][n] ----------------
__global__ __launch_bounds__(256) void k_gemm_z(const unsigned short* __restrict__ Xq,
                                                const unsigned short* __restrict__ Xk,
                                                const unsigned short* __restrict__ basesT,
                                                unsigned short* __restrict__ zT){
  __shared__ __align__(16) char smem[98816];
  unsigned short* ldsA = (unsigned short*)smem;            // staging A [128][64]
  unsigned short* ldsB = (unsigned short*)(smem + 16384);  // staging B [128][64]
  float* scores        = (float*)smem;                     // [128][129] f32, aliases staging
  unsigned short* zt   = (unsigned short*)(smem + 66048);  // [128 k][128 n] bf16
  int tid = threadIdx.x, lane = tid & 63, wid = tid >> 6, wr = wid >> 1, wc = wid & 1;
  int m0 = blockIdx.x*128, sb = blockIdx.y;
  const unsigned short* Xsb = ((sb >= 8) ? Xk : Xq) + (sb & 7)*(NSEQ*C4);
  const unsigned short* Bt  = basesT + sb*(128*C4);
  f32x4 acc[4][4] = {};
  for (int k0 = 0; k0 < C4; k0 += 64){
    __syncthreads();
    stage128x64(Xsb, m0, C4, k0, ldsA, tid);
    stage128x64(Bt,  0,  C4, k0, ldsB, tid);
    __syncthreads();
    mma_tiles<64,2>(ldsA, ldsB, acc, wr, wc, lane);
  }
  __syncthreads();
  int colg = lane & 15, rowg = (lane >> 4) * 4;
#pragma unroll
  for (int mf = 0; mf < 4; ++mf)
#pragma unroll
    for (int nf = 0; nf < 4; ++nf)
#pragma unroll
      for (int r = 0; r < 4; ++r)
        scores[(wr*64 + mf*16 + rowg + r)*129 + wc*64 + nf*16 + colg] = acc[mf][nf][r];
  __syncthreads();
  if (tid < 128){
    float mx = -3e38f;
    for (int j = 0; j < 128; ++j) mx = fmaxf(mx, scores[tid*129 + j]);
    float s = 0.f;
    for (int j = 0; j < 128; ++j){ float e = __expf(scores[tid*129 + j] - mx); scores[tid*129 + j] = e; s += e; }
    float inv = 1.f / s;
    for (int j = 0; j < 128; ++j) zt[j*128 + tid] = f2b(scores[tid*129 + j] * inv);
  }
  __syncthreads();
#pragma unroll
  for (int i = 0; i < 8; ++i){
    int cid = i*256 + tid;               // 2048 chunks of 16B
    int kk = cid >> 4, n8 = cid & 15;
    *(uint4*)(zT + sb*(128*NSEQ) + kk*NSEQ + m0 + n8*8) = *(const uint4*)(zt + cid*8);
  }
}

// ---------------- bases update: basesRaw[sb][k][c] = sum_n zT[k,n] * X[n,c] ----------------
__global__ __launch_bounds__(256) void k_gemm_bases(const unsigned short* __restrict__ Xq,
                                                    const unsigned short* __restrict__ Xk,
                                                    const unsigned short* __restrict__ zT,
                                                    float* __restrict__ basesRaw){
  __shared__ __align__(16) unsigned short ldsA[128*64];
  __shared__ __align__(16) unsigned short ldsB[128*64];   // X transposed: [128 c][64 n]
  int tid = threadIdx.x, lane = tid & 63, wid = tid >> 6, wr = wid >> 1, wc = wid & 1;
  int n0 = blockIdx.x*128, sb = blockIdx.y;
  const unsigned short* Xsb = ((sb >= 8) ? Xk : Xq) + (sb & 7)*(NSEQ*C4);
  const unsigned short* Zt  = zT + sb*(128*NSEQ);
  f32x4 acc[4][4] = {};
  for (int k0 = 0; k0 < NSEQ; k0 += 64){
    __syncthreads();
    stage128x64(Zt, 0, NSEQ, k0, ldsA, tid);
#pragma unroll
    for (int i = 0; i < 4; ++i){
      int cid = i*256 + tid;
      int np = cid >> 4, c8 = cid & 15;
      u16x8 v = *(const u16x8*)(Xsb + (k0 + np)*C4 + n0 + c8*8);
#pragma unroll
      for (int j = 0; j < 8; ++j) ldsB[(c8*8 + j)*64 + np] = v[j];
    }
    __syncthreads();
    mma_tiles<64,2>(ldsA, ldsB, acc, wr, wc, lane);
  }
  int colg = lane & 15, rowg = (lane >> 4) * 4;
#pragma unroll
  for (int mf = 0; mf < 4; ++mf)
#pragma unroll
    for (int nf = 0; nf < 4; ++nf)
#pragma unroll
      for (int r = 0; r < 4; ++r)
        basesRaw[sb*(128*C4) + (wr*64 + mf*16 + rowg + r)*C4 + n0 + wc*64 + nf*16 + colg] = acc[mf][nf][r];
}

// ---------------- att per (b,h): softmax_e(SCALE * qh.kh) ; store attT[e][d] ----------------
__global__ __launch_bounds__(256) void k_attn(const unsigned short* __restrict__ basesT,
                                              unsigned short* __restrict__ attT){
  __shared__ __align__(16) char smem[98816];
  unsigned short* Qlt = (unsigned short*)smem;             // [128 d][128 k]
  unsigned short* Klt = (unsigned short*)(smem + 32768);   // [128 e][128 k]
  float* scores       = (float*)smem;                      // [128][129], aliases operands (post-MMA)
  unsigned short* at  = (unsigned short*)(smem + 66048);   // [128 e][128 d]
  int tid = threadIdx.x, lane = tid & 63, wid = tid >> 6, wr = wid >> 1, wc = wid & 1;
  int b = blockIdx.x >> 3, h = blockIdx.x & 7;
  const unsigned short* Q = basesT + b*(128*C4) + h*128;
  const unsigned short* K = basesT + (8 + b)*(128*C4) + h*128;
#pragma unroll
  for (int i = 0; i < 8; ++i){
    int cid = i*256 + tid, kk = cid >> 4, c8 = cid & 15;
    u16x8 vq = *(const u16x8*)(Q + kk*C4 + c8*8);
    u16x8 vk = *(const u16x8*)(K + kk*C4 + c8*8);
#pragma unroll
    for (int j = 0; j < 8; ++j){
      Qlt[(c8*8 + j)*128 + kk] = vq[j];
      Klt[(c8*8 + j)*128 + kk] = vk[j];
    }
  }
  __syncthreads();
  f32x4 acc[4][4] = {};
  mma_tiles<128,4>(Qlt, Klt, acc, wr, wc, lane);
  __syncthreads();
  int colg = lane & 15, rowg = (lane >> 4) * 4;
#pragma unroll
  for (int mf = 0; mf < 4; ++mf)
#pragma unroll
    for (int nf = 0; nf < 4; ++nf)
#pragma unroll
      for (int r = 0; r < 4; ++r)
        scores[(wr*64 + mf*16 + rowg + r)*129 + wc*64 + nf*16 + colg] = acc[mf][nf][r] * SCALE_F;
  __syncthreads();
  if (tid < 128){
    float mx = -3e38f;
    for (int j = 0; j < 128; ++j) mx = fmaxf(mx, scores[tid*129 + j]);
    float s = 0.f;
    for (int j = 0; j < 128; ++j){ float e = __expf(scores[tid*129 + j] - mx); scores[tid*129 + j] = e; s += e; }
    float inv = 1.f / s;
    for (int j = 0; j < 128; ++j) at[j*128 + tid] = f2b(scores[tid*129 + j] * inv);
  }
  __syncthreads();
#pragma unroll
  for (int i = 0; i < 8; ++i){
    int cid = i*256 + tid;
    *(uint4*)(attT + blockIdx.x*16384 + cid*8) = *(const uint4*)(at + cid*8);
  }
}

// ---------------- WpEff[b][c][h*128+e] = sum_d Wp[c,h*128+d] * att[d,e] ----------------
__global__ __launch_bounds__(256) void k_wpeff(const unsigned short* __restrict__ Wpbf,
                                               const unsigned short* __restrict__ attT,
                                               unsigned short* __restrict__ WpEff){
  __shared__ __align__(16) unsigned short ldsA[128*64];
  __shared__ __align__(16) unsigned short ldsB[128*64];
  int tid = threadIdx.x, lane = tid & 63, wid = tid >> 6, wr = wid >> 1, wc = wid & 1;
  int m0 = blockIdx.x*128;                 // c tile (0/1)
  int bh = blockIdx.y, b = bh >> 3, h = bh & 7;
  const unsigned short* At = attT + bh*16384;  // [e][d], ld 128
  f32x4 acc[4][4] = {};
  for (int k0 = 0; k0 < 128; k0 += 64){
    __syncthreads();
    stage128x64(Wpbf, m0, C4, h*128 + k0, ldsA, tid);
    stage128x64(At,   0,  128, k0, ldsB, tid);
    __syncthreads();
    mma_tiles<64,2>(ldsA, ldsB, acc, wr, wc, lane);
  }
  int colg = lane & 15, rowg = (lane >> 4) * 4;
#pragma unroll
  for (int mf = 0; mf < 4; ++mf)
#pragma unroll
    for (int nf = 0; nf < 4; ++nf)
#pragma unroll
      for (int r = 0; r < 4; ++r){
        int row = m0 + wr*64 + mf*16 + rowg + r;
        int col = wc*64 + nf*16 + colg;
        WpEff[b*(256*C4) + row*C4 + h*128 + col] = f2b(acc[mf][nf][r]);
      }
}

// ---------------- W2[b][c][j] = sum_c4 WpEff[b][c][c4] * WvT[j][c4] ----------------
__global__ __launch_bounds__(256) void k_gemm_w2(const unsigned short* __restrict__ WpEff,
                                                 const unsigned short* __restrict__ WvT,
                                                 unsigned short* __restrict__ W2){
  __shared__ __align__(16) unsigned short ldsA[128*64];
  __shared__ __align__(16) unsigned short ldsB[128*64];
  int tid = threadIdx.x, lane = tid & 63, wid = tid >> 6, wr = wid >> 1, wc = wid & 1;
  int m0 = blockIdx.x*128, n0 = blockIdx.y*128, b = blockIdx.z;
  const unsigned short* A = WpEff + b*(256*C4);
  f32x4 acc[4][4] = {};
  for (int k0 = 0; k0 < C4; k0 += 64){
    __syncthreads();
    stage128x64(A,   m0, C4, k0, ldsA, tid);
    stage128x64(WvT, n0, C4, k0, ldsB, tid);
    __syncthreads();
    mma_tiles<64,2>(ldsA, ldsB, acc, wr, wc, lane);
  }
  int colg = lane & 15, rowg = (lane >> 4) * 4;
#pragma unroll
  for (int mf = 0; mf < 4; ++mf)
#pragma unroll
    for (int nf = 0; nf < 4; ++nf)
#pragma unroll
      for (int r = 0; r < 4; ++r){
        int row = m0 + wr*64 + mf*16 + rowg + r;
        int col = n0 + wc*64 + nf*16 + colg;
        W2[b*65536 + row*256 + col] = f2b(acc[mf][nf][r]);
      }
}

// ---------------- out[b,n,c] = relu( sum_j x[b,n,j]*W2[b][c][j] + bp[c] ) ----------------
__global__ __launch_bounds__(256) void k_gemm_out(const unsigned short* __restrict__ xbf,
                                                  const unsigned short* __restrict__ W2,
                                                  const float* __restrict__ bp,
                                                  float* __restrict__ out){
  __shared__ __align__(16) unsigned short ldsA[128*64];
  __shared__ __align__(16) unsigned short ldsB[128*64];
  int tid = threadIdx.x, lane = tid & 63, wid = tid >> 6, wr = wid >> 1, wc = wid & 1;
  int m0 = blockIdx.x*128, n0 = blockIdx.y*128, b = blockIdx.z;
  const unsigned short* A = xbf + b*(NSEQ*256);
  const unsigned short* Bm = W2 + b*65536;
  f32x4 acc[4][4] = {};
  for (int k0 = 0; k0 < 256; k0 += 64){
    __syncthreads();
    stage128x64(A,  m0, 256, k0, ldsA, tid);
    stage128x64(Bm, n0, 256, k0, ldsB, tid);
    __syncthreads();
    mma_tiles<64,2>(ldsA, ldsB, acc, wr, wc, lane);
  }
  int colg = lane & 15, rowg = (lane >> 4) * 4;
#pragma unroll
  for (int mf = 0; mf < 4; ++mf)
#pragma unroll
    for (int nf = 0; nf < 4; ++nf){
      int col = n0 + wc*64 + nf*16 + colg;
      float bias = bp[col];
#pragma unroll
      for (int r = 0; r < 4; ++r){
        int row = m0 + wr*64 + mf*16 + rowg + r;
        out[(b*NSEQ + row)*256 + col] = fmaxf(acc[mf][nf][r] + bias, 0.f);
      }
    }
}

extern "C" void kernel_launch(void* const* d_in, const int* in_sizes, int n_in,
                              void* d_out, int out_size, void* d_ws, size_t ws_size,
                              hipStream_t stream){
  (void)in_sizes; (void)n_in; (void)out_size; (void)ws_size;
  const float* x  = (const float*)d_in[0];
  const float* Wq = (const float*)d_in[1];
  const float* Wk = (const float*)d_in[2];
  const float* Wv = (const float*)d_in[3];
  const float* Wp = (const float*)d_in[4];
  const float* bp = (const float*)d_in[5];
  float* out = (float*)d_out;
  char* ws = (char*)d_ws;

  unsigned short* Xq     = (unsigned short*)(ws + 0);          // 64 MB  [8][4096][1024] bf16
  unsigned short* Xk     = (unsigned short*)(ws + 67108864);   // 64 MB
  unsigned short* xbf    = (unsigned short*)(ws + 134217728);  // 16 MB  [32768][256] bf16
  unsigned short* zT     = (unsigned short*)(ws + 150994944);  // 16 MB  [16][128][4096] bf16
  float*          bRaw   = (float*)(ws + 167772160);           // 8 MB   [16][128][1024] f32
  unsigned short* basesT = (unsigned short*)(ws + 176160768);  // 4 MB   [16][128][1024] bf16
  unsigned short* WpEff  = (unsigned short*)(ws + 180355072);  // 4 MB   [8][256][1024] bf16
  unsigned short* attT   = (unsigned short*)(ws + 184549376);  // 2 MB   [64][128][128] bf16
  unsigned short* Wcat   = (unsigned short*)(ws + 186646528);  // 1 MB   [2048][256] bf16 (Wq;Wk)
  unsigned short* WvT    = (unsigned short*)(ws + 187695104);  // 0.5 MB [256][1024] bf16
  unsigned short* Wpbf   = (unsigned short*)(ws + 188219392);  // 0.5 MB [256][1024] bf16
  unsigned short* W2     = (unsigned short*)(ws + 188743680);  // 1 MB   [8][256][256] bf16

  k_cast<<<8192, 256, 0, stream>>>(x,  xbf, 8388608);
  k_cast<<<256,  256, 0, stream>>>(Wq, Wcat,          262144);
  k_cast<<<256,  256, 0, stream>>>(Wk, Wcat + 262144, 262144);
  k_cast<<<256,  256, 0, stream>>>(Wp, Wpbf,          262144);
  k_transpose_wv<<<1024, 256, 0, stream>>>(Wv, WvT);

  k_gemm_qk<<<dim3(256, 16), 256, 0, stream>>>(xbf, Wcat, Xq, Xk);

  k_pool<<<dim3(128, 16), 256, 0, stream>>>(Xq, Xk, bRaw);
  k_norm<<<2048, 256, 0, stream>>>(bRaw, basesT);

  for (int st = 0; st < 3; ++st){
    k_gemm_z<<<dim3(32, 16), 256, 0, stream>>>(Xq, Xk, basesT, zT);
    k_gemm_bases<<<dim3(8, 16), 256, 0, stream>>>(Xq, Xk, zT, bRaw);
    k_norm<<<2048, 256, 0, stream>>>(bRaw, basesT);
  }

  k_attn<<<64, 256, 0, stream>>>(basesT, attT);
  k_wpeff<<<dim3(2, 64), 256, 0, stream>>>(Wpbf, attT, WpEff);
  k_gemm_w2<<<dim3(2, 2, 8), 256, 0, stream>>>(WpEff, WvT, W2);
  k_gemm_out<<<dim3(32, 2, 8), 256, 0, stream>>>(xbf, W2, bp, out);
}

// Round 2
// 484.112 us; speedup vs baseline: 1.8756x; 1.8756x over previous
//
#include <hip/hip_runtime.h>
#include <hip/hip_bf16.h>

// Problem constants
#define NSEQ 4096
#define C4   1024
#define SCALE_F 0.17677669529663687f   // (256/8)^-0.5
#define BSLICE 2097152                 // floats per bases-partial slice: 16*128*1024

typedef __attribute__((ext_vector_type(8))) short bf16x8;
typedef __attribute__((ext_vector_type(4))) float f32x4;
typedef __attribute__((ext_vector_type(8))) unsigned short u16x8;
typedef __attribute__((ext_vector_type(4))) unsigned short u16x4;

__device__ __forceinline__ float b2f(unsigned short b){
  union{unsigned u; float f;} v; v.u = ((unsigned)b)<<16; return v.f;
}
__device__ __forceinline__ unsigned short f2b(float x){
  union{float f; unsigned u;} v; v.f = x;
  unsigned r = v.u + 0x7fffu + ((v.u>>16)&1u);
  return (unsigned short)(r>>16);
}

typedef __attribute__((address_space(1))) void* gas_p;
typedef __attribute__((address_space(3))) void* las_p;
#define GLDS16(gp, lp) __builtin_amdgcn_global_load_lds((gas_p)(gp), (las_p)(lp), 16, 0, 0)

// Stage a 128x64 bf16 tile from row-major global (leading dim ld) into linear LDS [128][64].
__device__ __forceinline__ void stage128x64(const unsigned short* G, int row0, int ld, int k0,
                                            unsigned short* lds, int tid){
#pragma unroll
  for (int i = 0; i < 4; ++i){
    int cid = i*256 + tid;          // 1024 chunks of 16B
    int r = cid >> 3, c8 = cid & 7;
    GLDS16(G + (row0 + r)*ld + k0 + c8*8, lds + cid*8);
  }
}

// MFMA over staged tiles. ldsA/ldsB row-major [128][LD] bf16, NK = LD/32 k-chunks.
// Computes D[m,n] += sum_k A[m,k]*B[n,k]  (both operands reduction-contiguous).
// SWZB: B tile was stored with np ^= ((col>>3)&7)<<3 swizzle (bank-conflict fix).
template<int LD, int NK, bool SWZB = false>
__device__ __forceinline__ void mma_tiles(const unsigned short* ldsA, const unsigned short* ldsB,
                                          f32x4 acc[4][4], int wr, int wc, int lane){
  const int rowg = lane & 15, kg = (lane >> 4) * 8;
#pragma unroll
  for (int kc = 0; kc < NK; ++kc){
    bf16x8 a[4], b[4];
#pragma unroll
    for (int mf = 0; mf < 4; ++mf)
      a[mf] = *(const bf16x8*)(ldsA + (wr*64 + mf*16 + rowg)*LD + kc*32 + kg);
#pragma unroll
    for (int nf = 0; nf < 4; ++nf){
      int col = wc*64 + nf*16 + rowg;
      int np = kc*32 + kg;
      if constexpr (SWZB) np ^= ((col>>3)&7)<<3;
      b[nf] = *(const bf16x8*)(ldsB + col*LD + np);
    }
#pragma unroll
    for (int mf = 0; mf < 4; ++mf)
#pragma unroll
      for (int nf = 0; nf < 4; ++nf)
        acc[mf][nf] = __builtin_amdgcn_mfma_f32_16x16x32_bf16(a[mf], b[nf], acc[mf][nf], 0, 0, 0);
  }
}

// ---------------- casts ----------------
__global__ __launch_bounds__(256) void k_cast(const float* __restrict__ src,
                                              unsigned short* __restrict__ dst, int n){
  int i = (blockIdx.x*256 + threadIdx.x) * 4;
  if (i < n){
    float4 v = *(const float4*)(src + i);
    u16x4 o = { f2b(v.x), f2b(v.y), f2b(v.z), f2b(v.w) };
    *(u16x4*)(dst + i) = o;
  }
}

// WvT[j][c4] = Wv[c4][j], bf16.  Wv: [1024][256] f32.
__global__ __launch_bounds__(256) void k_transpose_wv(const float* __restrict__ Wv,
                                                      unsigned short* __restrict__ WvT){
  int t = blockIdx.x*256 + threadIdx.x;      // 262144 threads
  int j = t & 255, r = t >> 8;
  WvT[j*C4 + r] = f2b(Wv[r*256 + j]);
}

// ---------------- q/k projection: C[m,j] = sum_k x[m,k] * Wcat[j,k] ----------------
__global__ __launch_bounds__(256) void k_gemm_qk(const unsigned short* __restrict__ xbf,
                                                 const unsigned short* __restrict__ Wcat,
                                                 unsigned short* __restrict__ Xq,
                                                 unsigned short* __restrict__ Xk){
  __shared__ __align__(16) unsigned short ldsA[128*64];
  __shared__ __align__(16) unsigned short ldsB[128*64];
  int tid = threadIdx.x, lane = tid & 63, wid = tid >> 6, wr = wid >> 1, wc = wid & 1;
  int m0 = blockIdx.x*128, n0 = blockIdx.y*128;
  f32x4 acc[4][4] = {};
  for (int k0 = 0; k0 < 256; k0 += 64){
    __syncthreads();
    stage128x64(xbf,  m0, 256, k0, ldsA, tid);
    stage128x64(Wcat, n0, 256, k0, ldsB, tid);
    __syncthreads();
    mma_tiles<64,2>(ldsA, ldsB, acc, wr, wc, lane);
  }
  int colg = lane & 15, rowg = (lane >> 4) * 4;
#pragma unroll
  for (int mf = 0; mf < 4; ++mf)
#pragma unroll
    for (int nf = 0; nf < 4; ++nf){
      int col = n0 + wc*64 + nf*16 + colg;
      unsigned short* dst = (col < 1024) ? Xq : Xk;
      int c4 = col & 1023;
#pragma unroll
      for (int r = 0; r < 4; ++r){
        int row = m0 + wr*64 + mf*16 + rowg + r;
        dst[row*C4 + c4] = f2b(acc[mf][nf][r]);
      }
    }
}

// ---------------- adaptive max pool: bRawPart[0][sb][k][c] = max over 32-window ----------------
__global__ __launch_bounds__(256) void k_pool(const unsigned short* __restrict__ Xq,
                                              const unsigned short* __restrict__ Xk,
                                              float* __restrict__ basesRaw){
  int k = blockIdx.x, sb = blockIdx.y, tid = threadIdx.x;
  const unsigned short* Xsb = ((sb >= 8) ? Xk : Xq) + (sb & 7) * (NSEQ*C4);
  int c0 = tid * 4;
  float m0 = -3e38f, m1 = -3e38f, m2 = -3e38f, m3 = -3e38f;
  for (int nn = 0; nn < 32; ++nn){
    u16x4 v = *(const u16x4*)(Xsb + (k*32 + nn)*C4 + c0);
    m0 = fmaxf(m0, b2f(v[0])); m1 = fmaxf(m1, b2f(v[1]));
    m2 = fmaxf(m2, b2f(v[2])); m3 = fmaxf(m3, b2f(v[3]));
  }
  float4 o = { m0, m1, m2, m3 };
  *(float4*)(basesRaw + (sb*128 + k)*C4 + c0) = o;
}

// ---------------- l2-normalize (sum S partial slices) rows over c -> basesT bf16 ----------------
__global__ __launch_bounds__(256) void k_norm(const float* __restrict__ bRawPart,
                                              unsigned short* __restrict__ basesT, int S){
  int row = blockIdx.x, tid = threadIdx.x, lane = tid & 63, wid = tid >> 6;
  float4 v = {0.f, 0.f, 0.f, 0.f};
  for (int s = 0; s < S; ++s){
    float4 u = *(const float4*)(bRawPart + s*BSLICE + row*C4 + tid*4);
    v.x += u.x; v.y += u.y; v.z += u.z; v.w += u.w;
  }
  float ss = v.x*v.x + v.y*v.y + v.z*v.z + v.w*v.w;
  __shared__ float red[5];
#pragma unroll
  for (int o = 32; o; o >>= 1) ss += __shfl_down(ss, o);
  if (lane == 0) red[wid] = ss;
  __syncthreads();
  if (tid == 0) red[4] = 1.f / (1e-6f + sqrtf(red[0] + red[1] + red[2] + red[3]));
  __syncthreads();
  float inv = red[4];
  u16x4 o4 = { f2b(v.x*inv), f2b(v.y*inv), f2b(v.z*inv), f2b(v.w*inv) };
  *(u16x4*)(basesT + row*C4 + tid*4) = o4;
}

// ---------------- z-step: scores[n,k] = X[n,:].basesT[k,:]; softmax over k; store zT[k][n] ----------------
__global__ __launch_bounds__(256) void k_gemm_z(const unsigned short* __restrict__ Xq,
                                                const unsigned short* __restrict__ Xk,
                                                const unsigned short* __restrict__ basesT,
                                                unsigned short* __restrict__ zT){
  __shared__ __align__(16) char smem[98816];
  unsigned short* ldsA = (unsigned short*)smem;            // staging A [128][64]
  unsigned short* ldsB = (unsigned short*)(smem + 16384);  // staging B [128][64]
  float* scores        = (float*)smem;                     // [128][129] f32, aliases staging
  unsigned short* zt   = (unsigned short*)(smem + 66048);  // [128 k][128 n] bf16
  int tid = threadIdx.x, lane = tid & 63, wid = tid >> 6, wr = wid >> 1, wc = wid & 1;
  int m0 = blockIdx.x*128, sb = blockIdx.y;
  const unsigned short* Xsb = ((sb >= 8) ? Xk : Xq) + (sb & 7)*(NSEQ*C4);
  const unsigned short* Bt  = basesT + sb*(128*C4);
  f32x4 acc[4][4] = {};
  for (int k0 = 0; k0 < C4; k0 += 64){
    __syncthreads();
    stage128x64(Xsb, m0, C4, k0, ldsA, tid);
    stage128x64(Bt,  0,  C4, k0, ldsB, tid);
    __syncthreads();
    mma_tiles<64,2>(ldsA, ldsB, acc, wr, wc, lane);
  }
  __syncthreads();
  int colg = lane & 15, rowg = (lane >> 4) * 4;
#pragma unroll
  for (int mf = 0; mf < 4; ++mf)
#pragma unroll
    for (int nf = 0; nf < 4; ++nf)
#pragma unroll
      for (int r = 0; r < 4; ++r)
        scores[(wr*64 + mf*16 + rowg + r)*129 + wc*64 + nf*16 + colg] = acc[mf][nf][r];
  __syncthreads();
  if (tid < 128){
    float mx = -3e38f;
    for (int j = 0; j < 128; ++j) mx = fmaxf(mx, scores[tid*129 + j]);
    float s = 0.f;
    for (int j = 0; j < 128; ++j){ float e = __expf(scores[tid*129 + j] - mx); scores[tid*129 + j] = e; s += e; }
    float inv = 1.f / s;
    for (int j = 0; j < 128; ++j) zt[j*128 + tid] = f2b(scores[tid*129 + j] * inv);
  }
  __syncthreads();
#pragma unroll
  for (int i = 0; i < 8; ++i){
    int cid = i*256 + tid;               // 2048 chunks of 16B
    int kk = cid >> 4, n8 = cid & 15;
    *(uint4*)(zT + sb*(128*NSEQ) + kk*NSEQ + m0 + n8*8) = *(const uint4*)(zt + cid*8);
  }
}

// ---------------- bases update (split-K): bRawPart[ks][sb][k][c] = sum_{n in ks} zT[k,n] * X[n,c] ----------------
__global__ __launch_bounds__(256) void k_gemm_bases(const unsigned short* __restrict__ Xq,
                                                    const unsigned short* __restrict__ Xk,
                                                    const unsigned short* __restrict__ zT,
                                                    float* __restrict__ bRawPart){
  __shared__ __align__(16) unsigned short ldsA[128*64];
  __shared__ __align__(16) unsigned short ldsB[128*64];   // X transposed: [128 c][64 n], np-swizzled
  int tid = threadIdx.x, lane = tid & 63, wid = tid >> 6, wr = wid >> 1, wc = wid & 1;
  int c0 = blockIdx.x*128, sb = blockIdx.y, ks = blockIdx.z;
  const unsigned short* Xsb = ((sb >= 8) ? Xk : Xq) + (sb & 7)*(NSEQ*C4);
  const unsigned short* Zt  = zT + sb*(128*NSEQ);
  f32x4 acc[4][4] = {};
  for (int n0 = ks*1024; n0 < ks*1024 + 1024; n0 += 64){
    __syncthreads();
    stage128x64(Zt, 0, NSEQ, n0, ldsA, tid);
#pragma unroll
    for (int i = 0; i < 4; ++i){
      int cid = i*256 + tid;
      int np = cid >> 4, c8 = cid & 15;
      u16x8 v = *(const u16x8*)(Xsb + (n0 + np)*C4 + c0 + c8*8);
      int ps = np ^ ((c8 & 7) << 3);      // bank-spread swizzle (read side un-swizzles)
#pragma unroll
      for (int j = 0; j < 8; ++j) ldsB[(c8*8 + j)*64 + ps] = v[j];
    }
    __syncthreads();
    mma_tiles<64,2,true>(ldsA, ldsB, acc, wr, wc, lane);
  }
  int colg = lane & 15, rowg = (lane >> 4) * 4;
#pragma unroll
  for (int mf = 0; mf < 4; ++mf)
#pragma unroll
    for (int nf = 0; nf < 4; ++nf)
#pragma unroll
      for (int r = 0; r < 4; ++r)
        bRawPart[ks*BSLICE + (sb*128 + wr*64 + mf*16 + rowg + r)*C4 + c0 + wc*64 + nf*16 + colg]
          = acc[mf][nf][r];
}

// ---------------- att per (b,h): softmax_e(SCALE * qh.kh) ; store attT[e][d] ----------------
__global__ __launch_bounds__(256) void k_attn(const unsigned short* __restrict__ basesT,
                                              unsigned short* __restrict__ attT){
  __shared__ __align__(16) char smem[98816];
  unsigned short* Qlt = (unsigned short*)smem;             // [128 d][128 k]
  unsigned short* Klt = (unsigned short*)(smem + 32768);   // [128 e][128 k]
  float* scores       = (float*)smem;                      // [128][129], aliases operands (post-MMA)
  unsigned short* at  = (unsigned short*)(smem + 66048);   // [128 e][128 d]
  int tid = threadIdx.x, lane = tid & 63, wid = tid >> 6, wr = wid >> 1, wc = wid & 1;
  int b = blockIdx.x >> 3, h = blockIdx.x & 7;
  const unsigned short* Q = basesT + b*(128*C4) + h*128;
  const unsigned short* K = basesT + (8 + b)*(128*C4) + h*128;
#pragma unroll
  for (int i = 0; i < 8; ++i){
    int cid = i*256 + tid, kk = cid >> 4, c8 = cid & 15;
    u16x8 vq = *(const u16x8*)(Q + kk*C4 + c8*8);
    u16x8 vk = *(const u16x8*)(K + kk*C4 + c8*8);
#pragma unroll
    for (int j = 0; j < 8; ++j){
      Qlt[(c8*8 + j)*128 + kk] = vq[j];
      Klt[(c8*8 + j)*128 + kk] = vk[j];
    }
  }
  __syncthreads();
  f32x4 acc[4][4] = {};
  mma_tiles<128,4>(Qlt, Klt, acc, wr, wc, lane);
  __syncthreads();
  int colg = lane & 15, rowg = (lane >> 4) * 4;
#pragma unroll
  for (int mf = 0; mf < 4; ++mf)
#pragma unroll
    for (int nf = 0; nf < 4; ++nf)
#pragma unroll
      for (int r = 0; r < 4; ++r)
        scores[(wr*64 + mf*16 + rowg + r)*129 + wc*64 + nf*16 + colg] = acc[mf][nf][r] * SCALE_F;
  __syncthreads();
  if (tid < 128){
    float mx = -3e38f;
    for (int j = 0; j < 128; ++j) mx = fmaxf(mx, scores[tid*129 + j]);
    float s = 0.f;
    for (int j = 0; j < 128; ++j){ float e = __expf(scores[tid*129 + j] - mx); scores[tid*129 + j] = e; s += e; }
    float inv = 1.f / s;
    for (int j = 0; j < 128; ++j) at[j*128 + tid] = f2b(scores[tid*129 + j] * inv);
  }
  __syncthreads();
#pragma unroll
  for (int i = 0; i < 8; ++i){
    int cid = i*256 + tid;
    *(uint4*)(attT + blockIdx.x*16384 + cid*8) = *(const uint4*)(at + cid*8);
  }
}

// ---------------- WpEff[b][c][h*128+e] = sum_d Wp[c,h*128+d] * att[d,e] ----------------
__global__ __launch_bounds__(256) void k_wpeff(const unsigned short* __restrict__ Wpbf,
                                               const unsigned short* __restrict__ attT,
                                               unsigned short* __restrict__ WpEff){
  __shared__ __align__(16) unsigned short ldsA[128*64];
  __shared__ __align__(16) unsigned short ldsB[128*64];
  int tid = threadIdx.x, lane = tid & 63, wid = tid >> 6, wr = wid >> 1, wc = wid & 1;
  int m0 = blockIdx.x*128;                 // c tile (0/1)
  int bh = blockIdx.y, b = bh >> 3, h = bh & 7;
  const unsigned short* At = attT + bh*16384;  // [e][d], ld 128
  f32x4 acc[4][4] = {};
  for (int k0 = 0; k0 < 128; k0 += 64){
    __syncthreads();
    stage128x64(Wpbf, m0, C4, h*128 + k0, ldsA, tid);
    stage128x64(At,   0,  128, k0, ldsB, tid);
    __syncthreads();
    mma_tiles<64,2>(ldsA, ldsB, acc, wr, wc, lane);
  }
  int colg = lane & 15, rowg = (lane >> 4) * 4;
#pragma unroll
  for (int mf = 0; mf < 4; ++mf)
#pragma unroll
    for (int nf = 0; nf < 4; ++nf)
#pragma unroll
      for (int r = 0; r < 4; ++r){
        int row = m0 + wr*64 + mf*16 + rowg + r;
        int col = wc*64 + nf*16 + colg;
        WpEff[b*(256*C4) + row*C4 + h*128 + col] = f2b(acc[mf][nf][r]);
      }
}

// ---------------- W2[b][c][j] = sum_c4 WpEff[b][c][c4] * WvT[j][c4] ----------------
__global__ __launch_bounds__(256) void k_gemm_w2(const unsigned short* __restrict__ WpEff,
                                                 const unsigned short* __restrict__ WvT,
                                                 unsigned short* __restrict__ W2){
  __shared__ __align__(16) unsigned short ldsA[128*64];
  __shared__ __align__(16) unsigned short ldsB[128*64];
  int tid = threadIdx.x, lane = tid & 63, wid = tid >> 6, wr = wid >> 1, wc = wid & 1;
  int m0 = blockIdx.x*128, n0 = blockIdx.y*128, b = blockIdx.z;
  const unsigned short* A = WpEff + b*(256*C4);
  f32x4 acc[4][4] = {};
  for (int k0 = 0; k0 < C4; k0 += 64){
    __syncthreads();
    stage128x64(A,   m0, C4, k0, ldsA, tid);
    stage128x64(WvT, n0, C4, k0, ldsB, tid);
    __syncthreads();
    mma_tiles<64,2>(ldsA, ldsB, acc, wr, wc, lane);
  }
  int colg = lane & 15, rowg = (lane >> 4) * 4;
#pragma unroll
  for (int mf = 0; mf < 4; ++mf)
#pragma unroll
    for (int nf = 0; nf < 4; ++nf)
#pragma unroll
      for (int r = 0; r < 4; ++r){
        int row = m0 + wr*64 + mf*16 + rowg + r;
        int col = n0 + wc*64 + nf*16 + colg;
        W2[b*65536 + row*256 + col] = f2b(acc[mf][nf][r]);
      }
}

// ---------------- out[b,n,c] = relu( sum_j x[b,n,j]*W2[b][c][j] + bp[c] ) ----------------
__global__ __launch_bounds__(256) void k_gemm_out(const unsigned short* __restrict__ xbf,
                                                  const unsigned short* __restrict__ W2,
                                                  const float* __restrict__ bp,
                                                  float* __restrict__ out){
  __shared__ __align__(16) unsigned short ldsA[128*64];
  __shared__ __align__(16) unsigned short ldsB[128*64];
  int tid = threadIdx.x, lane = tid & 63, wid = tid >> 6, wr = wid >> 1, wc = wid & 1;
  int m0 = blockIdx.x*128, n0 = blockIdx.y*128, b = blockIdx.z;
  const unsigned short* A = xbf + b*(NSEQ*256);
  const unsigned short* Bm = W2 + b*65536;
  f32x4 acc[4][4] = {};
  for (int k0 = 0; k0 < 256; k0 += 64){
    __syncthreads();
    stage128x64(A,  m0, 256, k0, ldsA, tid);
    stage128x64(Bm, n0, 256, k0, ldsB, tid);
    __syncthreads();
    mma_tiles<64,2>(ldsA, ldsB, acc, wr, wc, lane);
  }
  int colg = lane & 15, rowg = (lane >> 4) * 4;
#pragma unroll
  for (int mf = 0; mf < 4; ++mf)
#pragma unroll
    for (int nf = 0; nf < 4; ++nf){
      int col = n0 + wc*64 + nf*16 + colg;
      float bias = bp[col];
#pragma unroll
      for (int r = 0; r < 4; ++r){
        int row = m0 + wr*64 + mf*16 + rowg + r;
        out[(b*NSEQ + row)*256 + col] = fmaxf(acc[mf][nf][r] + bias, 0.f);
      }
    }
}

extern "C" void kernel_launch(void* const* d_in, const int* in_sizes, int n_in,
                              void* d_out, int out_size, void* d_ws, size_t ws_size,
                              hipStream_t stream){
  (void)in_sizes; (void)n_in; (void)out_size; (void)ws_size;
  const float* x  = (const float*)d_in[0];
  const float* Wq = (const float*)d_in[1];
  const float* Wk = (const float*)d_in[2];
  const float* Wv = (const float*)d_in[3];
  const float* Wp = (const float*)d_in[4];
  const float* bp = (const float*)d_in[5];
  float* out = (float*)d_out;
  char* ws = (char*)d_ws;

  unsigned short* Xq     = (unsigned short*)(ws + 0);          // 64 MB  [8][4096][1024] bf16
  unsigned short* Xk     = (unsigned short*)(ws + 67108864);   // 64 MB
  unsigned short* xbf    = (unsigned short*)(ws + 134217728);  // 16 MB  [32768][256] bf16
  unsigned short* zT     = (unsigned short*)(ws + 150994944);  // 16 MB  [16][128][4096] bf16
  unsigned short* basesT = (unsigned short*)(ws + 167772160);  // 4 MB   [16][128][1024] bf16
  unsigned short* WpEff  = (unsigned short*)(ws + 171966464);  // 4 MB   [8][256][1024] bf16
  unsigned short* attT   = (unsigned short*)(ws + 176160768);  // 2 MB   [64][128][128] bf16
  unsigned short* Wcat   = (unsigned short*)(ws + 178257920);  // 1 MB   [2048][256] bf16 (Wq;Wk)
  unsigned short* WvT    = (unsigned short*)(ws + 179306496);  // 0.5 MB [256][1024] bf16
  unsigned short* Wpbf   = (unsigned short*)(ws + 179830784);  // 0.5 MB [256][1024] bf16
  unsigned short* W2     = (unsigned short*)(ws + 180355072);  // 1 MB   [8][256][256] bf16
  float*          bRawP  = (float*)(ws + 181403648);           // 32 MB  [4][16][128][1024] f32

  k_cast<<<8192, 256, 0, stream>>>(x,  xbf, 8388608);
  k_cast<<<256,  256, 0, stream>>>(Wq, Wcat,          262144);
  k_cast<<<256,  256, 0, stream>>>(Wk, Wcat + 262144, 262144);
  k_cast<<<256,  256, 0, stream>>>(Wp, Wpbf,          262144);
  k_transpose_wv<<<1024, 256, 0, stream>>>(Wv, WvT);

  k_gemm_qk<<<dim3(256, 16), 256, 0, stream>>>(xbf, Wcat, Xq, Xk);

  k_pool<<<dim3(128, 16), 256, 0, stream>>>(Xq, Xk, bRawP);
  k_norm<<<2048, 256, 0, stream>>>(bRawP, basesT, 1);

  for (int st = 0; st < 3; ++st){
    k_gemm_z<<<dim3(32, 16), 256, 0, stream>>>(Xq, Xk, basesT, zT);
    k_gemm_bases<<<dim3(8, 16, 4), 256, 0, stream>>>(Xq, Xk, zT, bRawP);
    k_norm<<<2048, 256, 0, stream>>>(bRawP, basesT, 4);
  }

  k_attn<<<64, 256, 0, stream>>>(basesT, attT);
  k_wpeff<<<dim3(2, 64), 256, 0, stream>>>(Wpbf, attT, WpEff);
  k_gemm_w2<<<dim3(2, 2, 8), 256, 0, stream>>>(WpEff, WvT, W2);
  k_gemm_out<<<dim3(32, 2, 8), 256, 0, stream>>>(xbf, W2, bp, out);
}

// Round 4
// 428.828 us; speedup vs baseline: 2.1175x; 1.1289x over previous
//
#include <hip/hip_runtime.h>
#include <hip/hip_bf16.h>

// Problem constants
#define NSEQ 4096
#define C4   1024
#define SCALE_F 0.17677669529663687f   // (256/8)^-0.5
#define BSLICE 2097152                 // floats per bases-partial slice: 16*128*1024

typedef __attribute__((ext_vector_type(8))) short bf16x8;
typedef __attribute__((ext_vector_type(4))) float f32x4;
typedef __attribute__((ext_vector_type(8))) unsigned short u16x8;
typedef __attribute__((ext_vector_type(4))) unsigned short u16x4;

__device__ __forceinline__ float b2f(unsigned short b){
  union{unsigned u; float f;} v; v.u = ((unsigned)b)<<16; return v.f;
}
__device__ __forceinline__ unsigned short f2b(float x){
  union{float f; unsigned u;} v; v.f = x;
  unsigned r = v.u + 0x7fffu + ((v.u>>16)&1u);
  return (unsigned short)(r>>16);
}
// monotone f32 <-> u32 mapping for atomicMax pooling
__device__ __forceinline__ unsigned mapf(float x){
  unsigned u = __float_as_uint(x);
  return (u & 0x80000000u) ? ~u : (u | 0x80000000u);
}
__device__ __forceinline__ float unmapf(unsigned m){
  unsigned u = (m & 0x80000000u) ? (m ^ 0x80000000u) : ~m;
  return __uint_as_float(u);
}

typedef __attribute__((address_space(1))) void* gas_p;
typedef __attribute__((address_space(3))) void* las_p;
#define GLDS16(gp, lp) __builtin_amdgcn_global_load_lds((gas_p)(gp), (las_p)(lp), 16, 0, 0)

#define WAITVM8() asm volatile("s_waitcnt vmcnt(8)" ::: "memory")
#define WAITVM4() asm volatile("s_waitcnt vmcnt(4)" ::: "memory")
#define WAITVM0() asm volatile("s_waitcnt vmcnt(0)" ::: "memory")
#define WAITLGKM() asm volatile("s_waitcnt lgkmcnt(0)" ::: "memory")
__device__ __forceinline__ void barrier(){
  asm volatile("" ::: "memory");
  __builtin_amdgcn_s_barrier();
  asm volatile("" ::: "memory");
}

// Stage a 128x64 bf16 tile from row-major global (leading dim ld) into linear LDS [128][64].
__device__ __forceinline__ void stage128x64(const unsigned short* G, int row0, int ld, int k0,
                                            unsigned short* lds, int tid){
#pragma unroll
  for (int i = 0; i < 4; ++i){
    int cid = i*256 + tid;          // 1024 chunks of 16B
    int r = cid >> 3, c8 = cid & 7;
    GLDS16(G + (row0 + r)*ld + k0 + c8*8, lds + cid*8);
  }
}

// MFMA over staged tiles. ldsA/ldsB row-major [128][LD] bf16, NK = LD/32 k-chunks.
// Computes D[m,n] += sum_k A[m,k]*B[n,k]  (both operands reduction-contiguous).
// SWZB: B tile was stored with np ^= ((col>>3)&7)<<3 swizzle (bank-conflict fix).
template<int LD, int NK, bool SWZB = false>
__device__ __forceinline__ void mma_tiles(const unsigned short* ldsA, const unsigned short* ldsB,
                                          f32x4 acc[4][4], int wr, int wc, int lane){
  const int rowg = lane & 15, kg = (lane >> 4) * 8;
#pragma unroll
  for (int kc = 0; kc < NK; ++kc){
    bf16x8 a[4], b[4];
#pragma unroll
    for (int mf = 0; mf < 4; ++mf)
      a[mf] = *(const bf16x8*)(ldsA + (wr*64 + mf*16 + rowg)*LD + kc*32 + kg);
#pragma unroll
    for (int nf = 0; nf < 4; ++nf){
      int col = wc*64 + nf*16 + rowg;
      int np = kc*32 + kg;
      if constexpr (SWZB) np ^= ((col>>3)&7)<<3;
      b[nf] = *(const bf16x8*)(ldsB + col*LD + np);
    }
#pragma unroll
    for (int mf = 0; mf < 4; ++mf)
#pragma unroll
      for (int nf = 0; nf < 4; ++nf)
        acc[mf][nf] = __builtin_amdgcn_mfma_f32_16x16x32_bf16(a[mf], b[nf], acc[mf][nf], 0, 0, 0);
  }
}

// ---------------- casts ----------------
__global__ __launch_bounds__(256) void k_cast(const float* __restrict__ src,
                                              unsigned short* __restrict__ dst, int n){
  int i = (blockIdx.x*256 + threadIdx.x) * 4;
  if (i < n){
    float4 v = *(const float4*)(src + i);
    u16x4 o = { f2b(v.x), f2b(v.y), f2b(v.z), f2b(v.w) };
    *(u16x4*)(dst + i) = o;
  }
}

// WvT[j][c4] = Wv[c4][j], bf16.  Wv: [1024][256] f32.
__global__ __launch_bounds__(256) void k_transpose_wv(const float* __restrict__ Wv,
                                                      unsigned short* __restrict__ WvT){
  int t = blockIdx.x*256 + threadIdx.x;      // 262144 threads
  int j = t & 255, r = t >> 8;
  WvT[j*C4 + r] = f2b(Wv[r*256 + j]);
}

// ---------------- q/k projection + fused adaptive-max-pool ----------------
// C[m,j] = sum_k x[m,k] * Wcat[j,k];  pooled[sb][kwin][c] = max over 32-row windows (atomicMax, mapped u32)
__global__ __launch_bounds__(256) void k_gemm_qk(const unsigned short* __restrict__ xbf,
                                                 const unsigned short* __restrict__ Wcat,
                                                 unsigned short* __restrict__ Xq,
                                                 unsigned short* __restrict__ Xk,
                                                 unsigned* __restrict__ pooled){
  __shared__ __align__(16) unsigned short ldsA[2][8192];
  __shared__ __align__(16) unsigned short ldsB[2][8192];
  int tid = threadIdx.x, lane = tid & 63, wid = tid >> 6, wr = wid >> 1, wc = wid & 1;
  int m0 = blockIdx.x*128, n0 = blockIdx.y*128;
  f32x4 acc[4][4] = {};
  stage128x64(xbf,  m0, 256, 0, ldsA[0], tid);
  stage128x64(Wcat, n0, 256, 0, ldsB[0], tid);
  for (int t = 0; t < 4; ++t){
    int cur = t & 1;
    if (t < 3){
      stage128x64(xbf,  m0, 256, (t+1)*64, ldsA[cur^1], tid);
      stage128x64(Wcat, n0, 256, (t+1)*64, ldsB[cur^1], tid);
      WAITVM8();
    } else WAITVM0();
    barrier();
    mma_tiles<64,2>(ldsA[cur], ldsB[cur], acc, wr, wc, lane);
    WAITLGKM();
    barrier();
  }
  int colg = lane & 15, rowg = (lane >> 4) * 4;
  int b = m0 >> 12, kbase = (m0 & 4095) >> 5;
#pragma unroll
  for (int mf = 0; mf < 4; ++mf)
#pragma unroll
    for (int nf = 0; nf < 4; ++nf){
      int col = n0 + wc*64 + nf*16 + colg;
      unsigned short* dst = (col < 1024) ? Xq : Xk;
      int c4 = col & 1023;
#pragma unroll
      for (int r = 0; r < 4; ++r){
        int row = m0 + wr*64 + mf*16 + rowg + r;
        dst[row*C4 + c4] = f2b(acc[mf][nf][r]);
      }
    }
  // fused pool: window = kbase + wr*2 (+1 for mf 2,3)
#pragma unroll
  for (int nf = 0; nf < 4; ++nf){
    float wlo = -3e38f, whi = -3e38f;
#pragma unroll
    for (int r = 0; r < 4; ++r){
      wlo = fmaxf(wlo, fmaxf(acc[0][nf][r], acc[1][nf][r]));
      whi = fmaxf(whi, fmaxf(acc[2][nf][r], acc[3][nf][r]));
    }
    wlo = fmaxf(wlo, __shfl_xor(wlo, 16)); wlo = fmaxf(wlo, __shfl_xor(wlo, 32));
    whi = fmaxf(whi, __shfl_xor(whi, 16)); whi = fmaxf(whi, __shfl_xor(whi, 32));
    if (lane < 16){
      int col = n0 + wc*64 + nf*16 + colg;
      int sbp = b + ((col >> 10) << 3);
      int c4 = col & 1023;
      atomicMax(&pooled[(sbp*128 + kbase + wr*2    )*C4 + c4], mapf(wlo));
      atomicMax(&pooled[(sbp*128 + kbase + wr*2 + 1)*C4 + c4], mapf(whi));
    }
  }
}

// ---------------- l2-normalize rows over c -> basesT bf16 ----------------
// S==0: decode mapped-u32 pooled; S>0: sum S f32 partial slices.
__global__ __launch_bounds__(256) void k_norm(const float* __restrict__ bRawPart,
                                              const unsigned* __restrict__ pooled,
                                              unsigned short* __restrict__ basesT, int S){
  int row = blockIdx.x, tid = threadIdx.x, lane = tid & 63, wid = tid >> 6;
  float4 v;
  if (S == 0){
    uint4 u = *(const uint4*)(pooled + row*C4 + tid*4);
    v.x = unmapf(u.x); v.y = unmapf(u.y); v.z = unmapf(u.z); v.w = unmapf(u.w);
  } else {
    v.x = v.y = v.z = v.w = 0.f;
    for (int s = 0; s < S; ++s){
      float4 u = *(const float4*)(bRawPart + s*BSLICE + row*C4 + tid*4);
      v.x += u.x; v.y += u.y; v.z += u.z; v.w += u.w;
    }
  }
  float ss = v.x*v.x + v.y*v.y + v.z*v.z + v.w*v.w;
  __shared__ float red[5];
#pragma unroll
  for (int o = 32; o; o >>= 1) ss += __shfl_down(ss, o);
  if (lane == 0) red[wid] = ss;
  __syncthreads();
  if (tid == 0) red[4] = 1.f / (1e-6f + sqrtf(red[0] + red[1] + red[2] + red[3]));
  __syncthreads();
  float inv = red[4];
  u16x4 o4 = { f2b(v.x*inv), f2b(v.y*inv), f2b(v.z*inv), f2b(v.w*inv) };
  *(u16x4*)(basesT + row*C4 + tid*4) = o4;
}

// ---------------- z-step: scores[n,k] = X[n,:].basesT[k,:]; softmax over k (in regs); store zT[k][n] ----------------
__global__ __launch_bounds__(256) void k_gemm_z(const unsigned short* __restrict__ Xq,
                                                const unsigned short* __restrict__ Xk,
                                                const unsigned short* __restrict__ basesT,
                                                unsigned short* __restrict__ zT){
  __shared__ __align__(16) unsigned short smem[32768];   // 64KB: A dbuf [0..16K), B dbuf [16K..32K)
  __shared__ float redb[2][2][128];                       // [max/sum][wc][row]
  unsigned short* zt = smem;                              // [128 k][128 n] bf16, aliases staging after loop
  int tid = threadIdx.x, lane = tid & 63, wid = tid >> 6, wr = wid >> 1, wc = wid & 1;
  int m0 = blockIdx.x*128, sb = blockIdx.y;
  const unsigned short* Xsb = ((sb >= 8) ? Xk : Xq) + (sb & 7)*(NSEQ*C4);
  const unsigned short* Bt  = basesT + sb*(128*C4);
  f32x4 acc[4][4] = {};
  stage128x64(Xsb, m0, C4, 0, smem, tid);
  stage128x64(Bt,  0,  C4, 0, smem + 16384, tid);
  for (int t = 0; t < 16; ++t){
    int cur = t & 1;
    if (t < 15){
      stage128x64(Xsb, m0, C4, (t+1)*64, smem + (cur^1)*8192, tid);
      stage128x64(Bt,  0,  C4, (t+1)*64, smem + 16384 + (cur^1)*8192, tid);
      WAITVM8();
    } else WAITVM0();
    barrier();
    mma_tiles<64,2>(smem + cur*8192, smem + 16384 + cur*8192, acc, wr, wc, lane);
    WAITLGKM();
    barrier();
  }
  int colg = lane & 15, rowg = (lane >> 4) * 4;
  // row max (over 128 k): local over nf, shfl over colg lanes, LDS over wc
  float sm[4][4];
#pragma unroll
  for (int mf = 0; mf < 4; ++mf)
#pragma unroll
    for (int r = 0; r < 4; ++r){
      float m = fmaxf(fmaxf(acc[mf][0][r], acc[mf][1][r]), fmaxf(acc[mf][2][r], acc[mf][3][r]));
#pragma unroll
      for (int o = 1; o < 16; o <<= 1) m = fmaxf(m, __shfl_xor(m, o));
      if (colg == 0) redb[0][wc][wr*64 + mf*16 + rowg + r] = m;
    }
  barrier();
#pragma unroll
  for (int mf = 0; mf < 4; ++mf)
#pragma unroll
    for (int r = 0; r < 4; ++r){
      int idx = wr*64 + mf*16 + rowg + r;
      float m = fmaxf(redb[0][0][idx], redb[0][1][idx]);
      float s = 0.f;
#pragma unroll
      for (int nf = 0; nf < 4; ++nf){
        float e = __expf(acc[mf][nf][r] - m);
        acc[mf][nf][r] = e; s += e;
      }
#pragma unroll
      for (int o = 1; o < 16; o <<= 1) s += __shfl_xor(s, o);
      if (colg == 0) redb[1][wc][idx] = s;
    }
  barrier();
#pragma unroll
  for (int mf = 0; mf < 4; ++mf)
#pragma unroll
    for (int r = 0; r < 4; ++r){
      int idx = wr*64 + mf*16 + rowg + r;
      sm[mf][r] = 1.f / (redb[1][0][idx] + redb[1][1][idx]);
    }
  // write z to zt (aliases staging; all staging reads retired at loop-end barrier)
#pragma unroll
  for (int mf = 0; mf < 4; ++mf)
#pragma unroll
    for (int nf = 0; nf < 4; ++nf){
      int k = wc*64 + nf*16 + colg;
      int swz = (k & 7) << 3;
#pragma unroll
      for (int r = 0; r < 4; ++r){
        int n = wr*64 + mf*16 + rowg + r;
        zt[k*128 + (n ^ swz)] = f2b(acc[mf][nf][r] * sm[mf][r]);
      }
    }
  WAITLGKM();
  barrier();
  // coalesced write-out, un-swizzling per 8-chunk
#pragma unroll
  for (int i = 0; i < 8; ++i){
    int cid = i*256 + tid;               // 2048 chunks of 16B
    int kk = cid >> 4, j8 = cid & 15;
    int nbase = (j8*8) ^ ((kk & 7) << 3);
    *(uint4*)(zT + sb*(128*NSEQ) + kk*NSEQ + m0 + nbase) = *(const uint4*)(zt + kk*128 + j8*8);
  }
}

// ---------------- bases update (split-K): bRawPart[ks][sb][k][c] = sum_{n in ks} zT[k,n] * X[n,c] ----------------
__global__ __launch_bounds__(256) void k_gemm_bases(const unsigned short* __restrict__ Xq,
                                                    const unsigned short* __restrict__ Xk,
                                                    const unsigned short* __restrict__ zT,
                                                    float* __restrict__ bRawPart){
  __shared__ __align__(16) unsigned short ldsA[2][8192];
  __shared__ __align__(16) unsigned short ldsB[2][8192];   // X^T: [128 c][64 n], np-swizzled
  int tid = threadIdx.x, lane = tid & 63, wid = tid >> 6, wr = wid >> 1, wc = wid & 1;
  int c0 = blockIdx.x*128, sb = blockIdx.y, ks = blockIdx.z;
  const unsigned short* Xsb = ((sb >= 8) ? Xk : Xq) + (sb & 7)*(NSEQ*C4);
  const unsigned short* Zt  = zT + sb*(128*NSEQ);
  int base = ks*1024;
  f32x4 acc[4][4] = {};
  u16x8 vB[4];
  int np_[4], c8_[4];
#pragma unroll
  for (int i = 0; i < 4; ++i){
    int cid = i*256 + tid;
    np_[i] = cid >> 4; c8_[i] = cid & 15;
  }
  // prologue
  stage128x64(Zt, 0, NSEQ, base, ldsA[0], tid);
#pragma unroll
  for (int i = 0; i < 4; ++i)
    vB[i] = *(const u16x8*)(Xsb + (base + np_[i])*C4 + c0 + c8_[i]*8);
  for (int t = 0; t < 16; ++t){
    int cur = t & 1, n0 = base + t*64;
    if (t < 15){
      stage128x64(Zt, 0, NSEQ, n0 + 64, ldsA[cur^1], tid);
      WAITVM4();
    } else WAITVM0();
    // ds_write B(t) from regs (swizzled)
#pragma unroll
    for (int i = 0; i < 4; ++i){
      int ps = np_[i] ^ ((c8_[i] & 7) << 3);
#pragma unroll
      for (int j = 0; j < 8; ++j) ldsB[cur][(c8_[i]*8 + j)*64 + ps] = vB[i][j];
    }
    WAITLGKM();
    barrier();
    if (t < 15){
#pragma unroll
      for (int i = 0; i < 4; ++i)
        vB[i] = *(const u16x8*)(Xsb + (n0 + 64 + np_[i])*C4 + c0 + c8_[i]*8);
    }
    mma_tiles<64,2,true>(ldsA[cur], ldsB[cur], acc, wr, wc, lane);
    WAITLGKM();
    barrier();
  }
  int colg = lane & 15, rowg = (lane >> 4) * 4;
#pragma unroll
  for (int mf = 0; mf < 4; ++mf)
#pragma unroll
    for (int nf = 0; nf < 4; ++nf)
#pragma unroll
      for (int r = 0; r < 4; ++r)
        bRawPart[ks*BSLICE + (sb*128 + wr*64 + mf*16 + rowg + r)*C4 + c0 + wc*64 + nf*16 + colg]
          = acc[mf][nf][r];
}

// ---------------- att per (b,h): softmax_e(SCALE * qh.kh) ; store attT[e][d] ----------------
__global__ __launch_bounds__(256) void k_attn(const unsigned short* __restrict__ basesT,
                                              unsigned short* __restrict__ attT){
  __shared__ __align__(16) char smem[98816];
  unsigned short* Qlt = (unsigned short*)smem;             // [128 d][128 k]
  unsigned short* Klt = (unsigned short*)(smem + 32768);   // [128 e][128 k]
  float* scores       = (float*)smem;                      // [128][129], aliases operands (post-MMA)
  unsigned short* at  = (unsigned short*)(smem + 66048);   // [128 e][128 d]
  int tid = threadIdx.x, lane = tid & 63, wid = tid >> 6, wr = wid >> 1, wc = wid & 1;
  int b = blockIdx.x >> 3, h = blockIdx.x & 7;
  const unsigned short* Q = basesT + b*(128*C4) + h*128;
  const unsigned short* K = basesT + (8 + b)*(128*C4) + h*128;
#pragma unroll
  for (int i = 0; i < 8; ++i){
    int cid = i*256 + tid, kk = cid >> 4, c8 = cid & 15;
    u16x8 vq = *(const u16x8*)(Q + kk*C4 + c8*8);
    u16x8 vk = *(const u16x8*)(K + kk*C4 + c8*8);
#pragma unroll
    for (int j = 0; j < 8; ++j){
      Qlt[(c8*8 + j)*128 + kk] = vq[j];
      Klt[(c8*8 + j)*128 + kk] = vk[j];
    }
  }
  __syncthreads();
  f32x4 acc[4][4] = {};
  mma_tiles<128,4>(Qlt, Klt, acc, wr, wc, lane);
  __syncthreads();
  int colg = lane & 15, rowg = (lane >> 4) * 4;
#pragma unroll
  for (int mf = 0; mf < 4; ++mf)
#pragma unroll
    for (int nf = 0; nf < 4; ++nf)
#pragma unroll
      for (int r = 0; r < 4; ++r)
        scores[(wr*64 + mf*16 + rowg + r)*129 + wc*64 + nf*16 + colg] = acc[mf][nf][r] * SCALE_F;
  __syncthreads();
  if (tid < 128){
    float mx = -3e38f;
    for (int j = 0; j < 128; ++j) mx = fmaxf(mx, scores[tid*129 + j]);
    float s = 0.f;
    for (int j = 0; j < 128; ++j){ float e = __expf(scores[tid*129 + j] - mx); scores[tid*129 + j] = e; s += e; }
    float inv = 1.f / s;
    for (int j = 0; j < 128; ++j) at[j*128 + tid] = f2b(scores[tid*129 + j] * inv);
  }
  __syncthreads();
#pragma unroll
  for (int i = 0; i < 8; ++i){
    int cid = i*256 + tid;
    *(uint4*)(attT + blockIdx.x*16384 + cid*8) = *(const uint4*)(at + cid*8);
  }
}

// ---------------- WpEff[b][c][h*128+e] = sum_d Wp[c,h*128+d] * att[d,e] ----------------
__global__ __launch_bounds__(256) void k_wpeff(const unsigned short* __restrict__ Wpbf,
                                               const unsigned short* __restrict__ attT,
                                               unsigned short* __restrict__ WpEff){
  __shared__ __align__(16) unsigned short ldsA[128*64];
  __shared__ __align__(16) unsigned short ldsB[128*64];
  int tid = threadIdx.x, lane = tid & 63, wid = tid >> 6, wr = wid >> 1, wc = wid & 1;
  int m0 = blockIdx.x*128;                 // c tile (0/1)
  int bh = blockIdx.y, b = bh >> 3, h = bh & 7;
  const unsigned short* At = attT + bh*16384;  // [e][d], ld 128
  f32x4 acc[4][4] = {};
  for (int k0 = 0; k0 < 128; k0 += 64){
    __syncthreads();
    stage128x64(Wpbf, m0, C4, h*128 + k0, ldsA, tid);
    stage128x64(At,   0,  128, k0, ldsB, tid);
    __syncthreads();
    mma_tiles<64,2>(ldsA, ldsB, acc, wr, wc, lane);
  }
  int colg = lane & 15, rowg = (lane >> 4) * 4;
#pragma unroll
  for (int mf = 0; mf < 4; ++mf)
#pragma unroll
    for (int nf = 0; nf < 4; ++nf)
#pragma unroll
      for (int r = 0; r < 4; ++r){
        int row = m0 + wr*64 + mf*16 + rowg + r;
        int col = wc*64 + nf*16 + colg;
        WpEff[b*(256*C4) + row*C4 + h*128 + col] = f2b(acc[mf][nf][r]);
      }
}

// ---------------- W2[b][c][j] = sum_c4 WpEff[b][c][c4] * WvT[j][c4] ----------------
__global__ __launch_bounds__(256) void k_gemm_w2(const unsigned short* __restrict__ WpEff,
                                                 const unsigned short* __restrict__ WvT,
                                                 unsigned short* __restrict__ W2){
  __shared__ __align__(16) unsigned short ldsA[128*64];
  __shared__ __align__(16) unsigned short ldsB[128*64];
  int tid = threadIdx.x, lane = tid & 63, wid = tid >> 6, wr = wid >> 1, wc = wid & 1;
  int m0 = blockIdx.x*128, n0 = blockIdx.y*128, b = blockIdx.z;
  const unsigned short* A = WpEff + b*(256*C4);
  f32x4 acc[4][4] = {};
  for (int k0 = 0; k0 < C4; k0 += 64){
    __syncthreads();
    stage128x64(A,   m0, C4, k0, ldsA, tid);
    stage128x64(WvT, n0, C4, k0, ldsB, tid);
    __syncthreads();
    mma_tiles<64,2>(ldsA, ldsB, acc, wr, wc, lane);
  }
  int colg = lane & 15, rowg = (lane >> 4) * 4;
#pragma unroll
  for (int mf = 0; mf < 4; ++mf)
#pragma unroll
    for (int nf = 0; nf < 4; ++nf)
#pragma unroll
      for (int r = 0; r < 4; ++r){
        int row = m0 + wr*64 + mf*16 + rowg + r;
        int col = n0 + wc*64 + nf*16 + colg;
        W2[b*65536 + row*256 + col] = f2b(acc[mf][nf][r]);
      }
}

// ---------------- out[b,n,c] = relu( sum_j x[b,n,j]*W2[b][c][j] + bp[c] ) ----------------
__global__ __launch_bounds__(256) void k_gemm_out(const unsigned short* __restrict__ xbf,
                                                  const unsigned short* __restrict__ W2,
                                                  const float* __restrict__ bp,
                                                  float* __restrict__ out){
  __shared__ __align__(16) unsigned short ldsA[2][8192];
  __shared__ __align__(16) unsigned short ldsB[2][8192];
  int tid = threadIdx.x, lane = tid & 63, wid = tid >> 6, wr = wid >> 1, wc = wid & 1;
  int m0 = blockIdx.x*128, n0 = blockIdx.y*128, b = blockIdx.z;
  const unsigned short* A = xbf + b*(NSEQ*256);
  const unsigned short* Bm = W2 + b*65536;
  f32x4 acc[4][4] = {};
  stage128x64(A,  m0, 256, 0, ldsA[0], tid);
  stage128x64(Bm, n0, 256, 0, ldsB[0], tid);
  for (int t = 0; t < 4; ++t){
    int cur = t & 1;
    if (t < 3){
      stage128x64(A,  m0, 256, (t+1)*64, ldsA[cur^1], tid);
      stage128x64(Bm, n0, 256, (t+1)*64, ldsB[cur^1], tid);
      WAITVM8();
    } else WAITVM0();
    barrier();
    mma_tiles<64,2>(ldsA[cur], ldsB[cur], acc, wr, wc, lane);
    WAITLGKM();
    barrier();
  }
  int colg = lane & 15, rowg = (lane >> 4) * 4;
#pragma unroll
  for (int mf = 0; mf < 4; ++mf)
#pragma unroll
    for (int nf = 0; nf < 4; ++nf){
      int col = n0 + wc*64 + nf*16 + colg;
      float bias = bp[col];
#pragma unroll
      for (int r = 0; r < 4; ++r){
        int row = m0 + wr*64 + mf*16 + rowg + r;
        out[(b*NSEQ + row)*256 + col] = fmaxf(acc[mf][nf][r] + bias, 0.f);
      }
    }
}

extern "C" void kernel_launch(void* const* d_in, const int* in_sizes, int n_in,
                              void* d_out, int out_size, void* d_ws, size_t ws_size,
                              hipStream_t stream){
  (void)in_sizes; (void)n_in; (void)out_size; (void)ws_size;
  const float* x  = (const float*)d_in[0];
  const float* Wq = (const float*)d_in[1];
  const float* Wk = (const float*)d_in[2];
  const float* Wv = (const float*)d_in[3];
  const float* Wp = (const float*)d_in[4];
  const float* bp = (const float*)d_in[5];
  float* out = (float*)d_out;
  char* ws = (char*)d_ws;

  unsigned short* Xq     = (unsigned short*)(ws + 0);          // 64 MB  [8][4096][1024] bf16
  unsigned short* Xk     = (unsigned short*)(ws + 67108864);   // 64 MB
  unsigned short* xbf    = (unsigned short*)(ws + 134217728);  // 16 MB  [32768][256] bf16
  unsigned short* zT     = (unsigned short*)(ws + 150994944);  // 16 MB  [16][128][4096] bf16
  unsigned short* basesT = (unsigned short*)(ws + 167772160);  // 4 MB   [16][128][1024] bf16
  unsigned short* WpEff  = (unsigned short*)(ws + 171966464);  // 4 MB   [8][256][1024] bf16
  unsigned short* attT   = (unsigned short*)(ws + 176160768);  // 2 MB   [64][128][128] bf16
  unsigned short* Wcat   = (unsigned short*)(ws + 178257920);  // 1 MB   [2048][256] bf16 (Wq;Wk)
  unsigned short* WvT    = (unsigned short*)(ws + 179306496);  // 0.5 MB [256][1024] bf16
  unsigned short* Wpbf   = (unsigned short*)(ws + 179830784);  // 0.5 MB [256][1024] bf16
  unsigned short* W2     = (unsigned short*)(ws + 180355072);  // 1 MB   [8][256][256] bf16
  float*          bRawP  = (float*)(ws + 181403648);           // 32 MB  [4][16][128][1024] f32
  unsigned*       pooled = (unsigned*)bRawP;                   // 8 MB, aliases bRawP slice 0 (dead at pool time)

  k_cast<<<8192, 256, 0, stream>>>(x,  xbf, 8388608);
  k_cast<<<256,  256, 0, stream>>>(Wq, Wcat,          262144);
  k_cast<<<256,  256, 0, stream>>>(Wk, Wcat + 262144, 262144);
  k_cast<<<256,  256, 0, stream>>>(Wp, Wpbf,          262144);
  k_transpose_wv<<<1024, 256, 0, stream>>>(Wv, WvT);

  (void)hipMemsetAsync(pooled, 0, (size_t)16*128*1024*4, stream);    // mapped -inf
  k_gemm_qk<<<dim3(256, 16), 256, 0, stream>>>(xbf, Wcat, Xq, Xk, pooled);
  k_norm<<<2048, 256, 0, stream>>>(bRawP, pooled, basesT, 0);

  for (int st = 0; st < 3; ++st){
    k_gemm_z<<<dim3(32, 16), 256, 0, stream>>>(Xq, Xk, basesT, zT);
    k_gemm_bases<<<dim3(8, 16, 4), 256, 0, stream>>>(Xq, Xk, zT, bRawP);
    k_norm<<<2048, 256, 0, stream>>>(bRawP, pooled, basesT, 4);
  }

  k_attn<<<64, 256, 0, stream>>>(basesT, attT);
  k_wpeff<<<dim3(2, 64), 256, 0, stream>>>(Wpbf, attT, WpEff);
  k_gemm_w2<<<dim3(2, 2, 8), 256, 0, stream>>>(WpEff, WvT, W2);
  k_gemm_out<<<dim3(32, 2, 8), 256, 0, stream>>>(xbf, W2, bp, out);
}

// Round 5
// 400.934 us; speedup vs baseline: 2.2648x; 1.0696x over previous
//
#include <hip/hip_runtime.h>
#include <hip/hip_bf16.h>

// Problem constants
#define NSEQ 4096
#define C4   1024
#define SCALE_F 0.17677669529663687f   // (256/8)^-0.5
#define BSLICE 2097152                 // floats per bases-partial slice: 16*128*1024

typedef __attribute__((ext_vector_type(8))) short bf16x8;
typedef __attribute__((ext_vector_type(4))) float f32x4;
typedef __attribute__((ext_vector_type(8))) unsigned short u16x8;
typedef __attribute__((ext_vector_type(4))) unsigned short u16x4;

__device__ __forceinline__ float b2f(unsigned short b){
  union{unsigned u; float f;} v; v.u = ((unsigned)b)<<16; return v.f;
}
__device__ __forceinline__ unsigned short f2b(float x){
  union{float f; unsigned u;} v; v.f = x;
  unsigned r = v.u + 0x7fffu + ((v.u>>16)&1u);
  return (unsigned short)(r>>16);
}
// monotone f32 <-> u32 mapping for atomicMax pooling
__device__ __forceinline__ unsigned mapf(float x){
  unsigned u = __float_as_uint(x);
  return (u & 0x80000000u) ? ~u : (u | 0x80000000u);
}
__device__ __forceinline__ float unmapf(unsigned m){
  unsigned u = (m & 0x80000000u) ? (m ^ 0x80000000u) : ~m;
  return __uint_as_float(u);
}

typedef __attribute__((address_space(1))) void* gas_p;
typedef __attribute__((address_space(3))) void* las_p;
#define GLDS16(gp, lp) __builtin_amdgcn_global_load_lds((gas_p)(gp), (las_p)(lp), 16, 0, 0)

#define WAITVM8() asm volatile("s_waitcnt vmcnt(8)" ::: "memory")
#define WAITVM4() asm volatile("s_waitcnt vmcnt(4)" ::: "memory")
#define WAITVM0() asm volatile("s_waitcnt vmcnt(0)" ::: "memory")
#define WAITLGKM() asm volatile("s_waitcnt lgkmcnt(0)" ::: "memory")
__device__ __forceinline__ void barrier(){
  asm volatile("" ::: "memory");
  __builtin_amdgcn_s_barrier();
  asm volatile("" ::: "memory");
}

// Stage a 128x64 bf16 tile, chunk-XOR swizzled: LDS slot (r,c8) holds global chunk (c8^(r&7)).
// Permutation stays inside each 128B row -> coalescing preserved. Readers use MA/MB==1.
__device__ __forceinline__ void stage128x64s(const unsigned short* G, int row0, int ld, int k0,
                                             unsigned short* lds, int tid){
#pragma unroll
  for (int i = 0; i < 4; ++i){
    int cid = i*256 + tid;          // 1024 chunks of 16B
    int r = cid >> 3, c8 = cid & 7;
    GLDS16(G + (row0 + r)*ld + k0 + ((c8 ^ (r & 7))*8), lds + cid*8);
  }
}

// MFMA over staged tiles. ldsA/ldsB row-major [128][LD] bf16, NK = LD/32 k-chunks.
// D[m,n] += sum_k A[m,k]*B[n,k]. Modes: 0=linear, 1=chunk-XOR (stage128x64s), 2=bases-B np-XOR.
template<int LD, int NK, int MA, int MB>
__device__ __forceinline__ void mma_tiles(const unsigned short* ldsA, const unsigned short* ldsB,
                                          f32x4 acc[4][4], int wr, int wc, int lane){
  const int rowg = lane & 15, q4 = lane >> 4;
#pragma unroll
  for (int kc = 0; kc < NK; ++kc){
    bf16x8 a[4], b[4];
#pragma unroll
    for (int mf = 0; mf < 4; ++mf){
      int row = wr*64 + mf*16 + rowg;
      int off;
      if constexpr (MA == 1) off = ((kc*4 + q4) ^ (row & 7)) * 8;
      else                   off = kc*32 + q4*8;
      a[mf] = *(const bf16x8*)(ldsA + row*LD + off);
    }
#pragma unroll
    for (int nf = 0; nf < 4; ++nf){
      int col = wc*64 + nf*16 + rowg;
      int off;
      if constexpr (MB == 1)      off = ((kc*4 + q4) ^ (col & 7)) * 8;
      else if constexpr (MB == 2) off = (kc*32 + q4*8) ^ ((((col>>3) ^ col) & 7) << 3);
      else                        off = kc*32 + q4*8;
      b[nf] = *(const bf16x8*)(ldsB + col*LD + off);
    }
#pragma unroll
    for (int mf = 0; mf < 4; ++mf)
#pragma unroll
      for (int nf = 0; nf < 4; ++nf)
        acc[mf][nf] = __builtin_amdgcn_mfma_f32_16x16x32_bf16(a[mf], b[nf], acc[mf][nf], 0, 0, 0);
  }
}

// ---------------- casts ----------------
__global__ __launch_bounds__(256) void k_cast(const float* __restrict__ src,
                                              unsigned short* __restrict__ dst, int n){
  int i = (blockIdx.x*256 + threadIdx.x) * 4;
  if (i < n){
    float4 v = *(const float4*)(src + i);
    u16x4 o = { f2b(v.x), f2b(v.y), f2b(v.z), f2b(v.w) };
    *(u16x4*)(dst + i) = o;
  }
}

// WvT[j][c4] = Wv[c4][j], bf16.  Wv: [1024][256] f32.
__global__ __launch_bounds__(256) void k_transpose_wv(const float* __restrict__ Wv,
                                                      unsigned short* __restrict__ WvT){
  int t = blockIdx.x*256 + threadIdx.x;      // 262144 threads
  int j = t & 255, r = t >> 8;
  WvT[j*C4 + r] = f2b(Wv[r*256 + j]);
}

// ---------------- q/k projection + fused adaptive-max-pool ----------------
// Single-buffer (32KB LDS, 5 blocks/CU): short-K GEMM lives on TLP, not pipeline depth.
__global__ __launch_bounds__(256) void k_gemm_qk(const unsigned short* __restrict__ xbf,
                                                 const unsigned short* __restrict__ Wcat,
                                                 unsigned short* __restrict__ Xq,
                                                 unsigned short* __restrict__ Xk,
                                                 unsigned* __restrict__ pooled){
  __shared__ __align__(16) unsigned short ldsA[128*64];
  __shared__ __align__(16) unsigned short ldsB[128*64];
  int tid = threadIdx.x, lane = tid & 63, wid = tid >> 6, wr = wid >> 1, wc = wid & 1;
  int m0 = blockIdx.x*128, n0 = blockIdx.y*128;
  f32x4 acc[4][4] = {};
  for (int k0 = 0; k0 < 256; k0 += 64){
    __syncthreads();
    stage128x64s(xbf,  m0, 256, k0, ldsA, tid);
    stage128x64s(Wcat, n0, 256, k0, ldsB, tid);
    __syncthreads();
    mma_tiles<64,2,1,1>(ldsA, ldsB, acc, wr, wc, lane);
  }
  int colg = lane & 15, rowg = (lane >> 4) * 4;
  int b = m0 >> 12, kbase = (m0 & 4095) >> 5;
#pragma unroll
  for (int mf = 0; mf < 4; ++mf)
#pragma unroll
    for (int nf = 0; nf < 4; ++nf){
      int col = n0 + wc*64 + nf*16 + colg;
      unsigned short* dst = (col < 1024) ? Xq : Xk;
      int c4 = col & 1023;
#pragma unroll
      for (int r = 0; r < 4; ++r){
        int row = m0 + wr*64 + mf*16 + rowg + r;
        dst[row*C4 + c4] = f2b(acc[mf][nf][r]);
      }
    }
  // fused pool: window = kbase + wr*2 (+1 for mf 2,3)
#pragma unroll
  for (int nf = 0; nf < 4; ++nf){
    float wlo = -3e38f, whi = -3e38f;
#pragma unroll
    for (int r = 0; r < 4; ++r){
      wlo = fmaxf(wlo, fmaxf(acc[0][nf][r], acc[1][nf][r]));
      whi = fmaxf(whi, fmaxf(acc[2][nf][r], acc[3][nf][r]));
    }
    wlo = fmaxf(wlo, __shfl_xor(wlo, 16)); wlo = fmaxf(wlo, __shfl_xor(wlo, 32));
    whi = fmaxf(whi, __shfl_xor(whi, 16)); whi = fmaxf(whi, __shfl_xor(whi, 32));
    if (lane < 16){
      int col = n0 + wc*64 + nf*16 + colg;
      int sbp = b + ((col >> 10) << 3);
      int c4 = col & 1023;
      atomicMax(&pooled[(sbp*128 + kbase + wr*2    )*C4 + c4], mapf(wlo));
      atomicMax(&pooled[(sbp*128 + kbase + wr*2 + 1)*C4 + c4], mapf(whi));
    }
  }
}

// ---------------- l2-normalize rows over c -> basesT bf16 ----------------
// S==0: decode mapped-u32 pooled; S>0: sum S f32 partial slices.
__global__ __launch_bounds__(256) void k_norm(const float* __restrict__ bRawPart,
                                              const unsigned* __restrict__ pooled,
                                              unsigned short* __restrict__ basesT, int S){
  int row = blockIdx.x, tid = threadIdx.x, lane = tid & 63, wid = tid >> 6;
  float4 v;
  if (S == 0){
    uint4 u = *(const uint4*)(pooled + row*C4 + tid*4);
    v.x = unmapf(u.x); v.y = unmapf(u.y); v.z = unmapf(u.z); v.w = unmapf(u.w);
  } else {
    v.x = v.y = v.z = v.w = 0.f;
    for (int s = 0; s < S; ++s){
      float4 u = *(const float4*)(bRawPart + s*BSLICE + row*C4 + tid*4);
      v.x += u.x; v.y += u.y; v.z += u.z; v.w += u.w;
    }
  }
  float ss = v.x*v.x + v.y*v.y + v.z*v.z + v.w*v.w;
  __shared__ float red[5];
#pragma unroll
  for (int o = 32; o; o >>= 1) ss += __shfl_down(ss, o);
  if (lane == 0) red[wid] = ss;
  __syncthreads();
  if (tid == 0) red[4] = 1.f / (1e-6f + sqrtf(red[0] + red[1] + red[2] + red[3]));
  __syncthreads();
  float inv = red[4];
  u16x4 o4 = { f2b(v.x*inv), f2b(v.y*inv), f2b(v.z*inv), f2b(v.w*inv) };
  *(u16x4*)(basesT + row*C4 + tid*4) = o4;
}

// ---------------- z-step: scores[n,k] = X[n,:].basesT[k,:]; softmax over k (in regs); store zT[k][n] ----------------
__global__ __launch_bounds__(256) void k_gemm_z(const unsigned short* __restrict__ Xq,
                                                const unsigned short* __restrict__ Xk,
                                                const unsigned short* __restrict__ basesT,
                                                unsigned short* __restrict__ zT){
  __shared__ __align__(16) unsigned short smem[32768];   // 64KB: A dbuf [0..16K), B dbuf [16K..32K)
  __shared__ float redb[2][2][128];                       // [max/sum][wc][row]
  unsigned short* zt = smem;                              // [128 k][128 n] bf16, aliases staging after loop
  int tid = threadIdx.x, lane = tid & 63, wid = tid >> 6, wr = wid >> 1, wc = wid & 1;
  int m0 = blockIdx.x*128, sb = blockIdx.y;
  const unsigned short* Xsb = ((sb >= 8) ? Xk : Xq) + (sb & 7)*(NSEQ*C4);
  const unsigned short* Bt  = basesT + sb*(128*C4);
  f32x4 acc[4][4] = {};
  stage128x64s(Xsb, m0, C4, 0, smem, tid);
  stage128x64s(Bt,  0,  C4, 0, smem + 16384, tid);
  for (int t = 0; t < 16; ++t){
    int cur = t & 1;
    if (t < 15){
      stage128x64s(Xsb, m0, C4, (t+1)*64, smem + (cur^1)*8192, tid);
      stage128x64s(Bt,  0,  C4, (t+1)*64, smem + 16384 + (cur^1)*8192, tid);
      WAITVM8();
    } else WAITVM0();
    barrier();
    mma_tiles<64,2,1,1>(smem + cur*8192, smem + 16384 + cur*8192, acc, wr, wc, lane);
    WAITLGKM();
    barrier();
  }
  int colg = lane & 15, rowg = (lane >> 4) * 4;
  // row max (over 128 k): local over nf, shfl over colg lanes, LDS over wc
  float sm[4][4];
#pragma unroll
  for (int mf = 0; mf < 4; ++mf)
#pragma unroll
    for (int r = 0; r < 4; ++r){
      float m = fmaxf(fmaxf(acc[mf][0][r], acc[mf][1][r]), fmaxf(acc[mf][2][r], acc[mf][3][r]));
#pragma unroll
      for (int o = 1; o < 16; o <<= 1) m = fmaxf(m, __shfl_xor(m, o));
      if (colg == 0) redb[0][wc][wr*64 + mf*16 + rowg + r] = m;
    }
  barrier();
#pragma unroll
  for (int mf = 0; mf < 4; ++mf)
#pragma unroll
    for (int r = 0; r < 4; ++r){
      int idx = wr*64 + mf*16 + rowg + r;
      float m = fmaxf(redb[0][0][idx], redb[0][1][idx]);
      float s = 0.f;
#pragma unroll
      for (int nf = 0; nf < 4; ++nf){
        float e = __expf(acc[mf][nf][r] - m);
        acc[mf][nf][r] = e; s += e;
      }
#pragma unroll
      for (int o = 1; o < 16; o <<= 1) s += __shfl_xor(s, o);
      if (colg == 0) redb[1][wc][idx] = s;
    }
  barrier();
#pragma unroll
  for (int mf = 0; mf < 4; ++mf)
#pragma unroll
    for (int r = 0; r < 4; ++r){
      int idx = wr*64 + mf*16 + rowg + r;
      sm[mf][r] = 1.f / (redb[1][0][idx] + redb[1][1][idx]);
    }
  // write z to zt (aliases staging; all staging reads retired at loop-end barrier)
#pragma unroll
  for (int mf = 0; mf < 4; ++mf)
#pragma unroll
    for (int nf = 0; nf < 4; ++nf){
      int k = wc*64 + nf*16 + colg;
      int swz = (k & 7) << 3;
#pragma unroll
      for (int r = 0; r < 4; ++r){
        int n = wr*64 + mf*16 + rowg + r;
        zt[k*128 + (n ^ swz)] = f2b(acc[mf][nf][r] * sm[mf][r]);
      }
    }
  WAITLGKM();
  barrier();
  // coalesced write-out, un-swizzling per 8-chunk
#pragma unroll
  for (int i = 0; i < 8; ++i){
    int cid = i*256 + tid;               // 2048 chunks of 16B
    int kk = cid >> 4, j8 = cid & 15;
    int nbase = (j8*8) ^ ((kk & 7) << 3);
    *(uint4*)(zT + sb*(128*NSEQ) + kk*NSEQ + m0 + nbase) = *(const uint4*)(zt + kk*128 + j8*8);
  }
}

// ---------------- bases update (split-K): bRawPart[ks][sb][k][c] = sum_{n in ks} zT[k,n] * X[n,c] ----------------
__global__ __launch_bounds__(256) void k_gemm_bases(const unsigned short* __restrict__ Xq,
                                                    const unsigned short* __restrict__ Xk,
                                                    const unsigned short* __restrict__ zT,
                                                    float* __restrict__ bRawPart){
  __shared__ __align__(16) unsigned short ldsA[2][8192];
  __shared__ __align__(16) unsigned short ldsB[2][8192];   // X^T: [128 c][64 n], np-XOR swizzled
  int tid = threadIdx.x, lane = tid & 63, wid = tid >> 6, wr = wid >> 1, wc = wid & 1;
  int c0 = blockIdx.x*128, sb = blockIdx.y, ks = blockIdx.z;
  const unsigned short* Xsb = ((sb >= 8) ? Xk : Xq) + (sb & 7)*(NSEQ*C4);
  const unsigned short* Zt  = zT + sb*(128*NSEQ);
  int base = ks*1024;
  f32x4 acc[4][4] = {};
  u16x8 vB[4];
  int np_[4], c8_[4];
#pragma unroll
  for (int i = 0; i < 4; ++i){
    int cid = i*256 + tid;
    np_[i] = cid >> 4; c8_[i] = cid & 15;
  }
  // prologue
  stage128x64s(Zt, 0, NSEQ, base, ldsA[0], tid);
#pragma unroll
  for (int i = 0; i < 4; ++i)
    vB[i] = *(const u16x8*)(Xsb + (base + np_[i])*C4 + c0 + c8_[i]*8);
  for (int t = 0; t < 16; ++t){
    int cur = t & 1, n0 = base + t*64;
    if (t < 15){
      stage128x64s(Zt, 0, NSEQ, n0 + 64, ldsA[cur^1], tid);
      WAITVM4();
    } else WAITVM0();
    // ds_write B(t) from regs; col c = c8*8+j, pos = np ^ (((c>>3)^c)&7)<<3 = np ^ ((c8^j)&7)<<3
#pragma unroll
    for (int i = 0; i < 4; ++i){
#pragma unroll
      for (int j = 0; j < 8; ++j)
        ldsB[cur][(c8_[i]*8 + j)*64 + (np_[i] ^ (((c8_[i] ^ j) & 7) << 3))] = vB[i][j];
    }
    WAITLGKM();
    barrier();
    if (t < 15){
#pragma unroll
      for (int i = 0; i < 4; ++i)
        vB[i] = *(const u16x8*)(Xsb + (n0 + 64 + np_[i])*C4 + c0 + c8_[i]*8);
    }
    mma_tiles<64,2,1,2>(ldsA[cur], ldsB[cur], acc, wr, wc, lane);
    WAITLGKM();
    barrier();
  }
  int colg = lane & 15, rowg = (lane >> 4) * 4;
#pragma unroll
  for (int mf = 0; mf < 4; ++mf)
#pragma unroll
    for (int nf = 0; nf < 4; ++nf)
#pragma unroll
      for (int r = 0; r < 4; ++r)
        bRawPart[ks*BSLICE + (sb*128 + wr*64 + mf*16 + rowg + r)*C4 + c0 + wc*64 + nf*16 + colg]
          = acc[mf][nf][r];
}

// ---------------- att per (b,h): softmax_e(SCALE * qh.kh) ; store attT[e][d] ----------------
__global__ __launch_bounds__(256) void k_attn(const unsigned short* __restrict__ basesT,
                                              unsigned short* __restrict__ attT){
  __shared__ __align__(16) char smem[98816];
  unsigned short* Qlt = (unsigned short*)smem;             // [128 d][128 k]
  unsigned short* Klt = (unsigned short*)(smem + 32768);   // [128 e][128 k]
  float* scores       = (float*)smem;                      // [128][129], aliases operands (post-MMA)
  unsigned short* at  = (unsigned short*)(smem + 66048);   // [128 e][128 d]
  int tid = threadIdx.x, lane = tid & 63, wid = tid >> 6, wr = wid >> 1, wc = wid & 1;
  int b = blockIdx.x >> 3, h = blockIdx.x & 7;
  const unsigned short* Q = basesT + b*(128*C4) + h*128;
  const unsigned short* K = basesT + (8 + b)*(128*C4) + h*128;
#pragma unroll
  for (int i = 0; i < 8; ++i){
    int cid = i*256 + tid, kk = cid >> 4, c8 = cid & 15;
    u16x8 vq = *(const u16x8*)(Q + kk*C4 + c8*8);
    u16x8 vk = *(const u16x8*)(K + kk*C4 + c8*8);
#pragma unroll
    for (int j = 0; j < 8; ++j){
      Qlt[(c8*8 + j)*128 + kk] = vq[j];
      Klt[(c8*8 + j)*128 + kk] = vk[j];
    }
  }
  __syncthreads();
  f32x4 acc[4][4] = {};
  mma_tiles<128,4,0,0>(Qlt, Klt, acc, wr, wc, lane);
  __syncthreads();
  int colg = lane & 15, rowg = (lane >> 4) * 4;
#pragma unroll
  for (int mf = 0; mf < 4; ++mf)
#pragma unroll
    for (int nf = 0; nf < 4; ++nf)
#pragma unroll
      for (int r = 0; r < 4; ++r)
        scores[(wr*64 + mf*16 + rowg + r)*129 + wc*64 + nf*16 + colg] = acc[mf][nf][r] * SCALE_F;
  __syncthreads();
  if (tid < 128){
    float mx = -3e38f;
    for (int j = 0; j < 128; ++j) mx = fmaxf(mx, scores[tid*129 + j]);
    float s = 0.f;
    for (int j = 0; j < 128; ++j){ float e = __expf(scores[tid*129 + j] - mx); scores[tid*129 + j] = e; s += e; }
    float inv = 1.f / s;
    for (int j = 0; j < 128; ++j) at[j*128 + tid] = f2b(scores[tid*129 + j] * inv);
  }
  __syncthreads();
#pragma unroll
  for (int i = 0; i < 8; ++i){
    int cid = i*256 + tid;
    *(uint4*)(attT + blockIdx.x*16384 + cid*8) = *(const uint4*)(at + cid*8);
  }
}

// ---------------- WpEff[b][c][h*128+e] = sum_d Wp[c,h*128+d] * att[d,e] ----------------
__global__ __launch_bounds__(256) void k_wpeff(const unsigned short* __restrict__ Wpbf,
                                               const unsigned short* __restrict__ attT,
                                               unsigned short* __restrict__ WpEff){
  __shared__ __align__(16) unsigned short ldsA[128*64];
  __shared__ __align__(16) unsigned short ldsB[128*64];
  int tid = threadIdx.x, lane = tid & 63, wid = tid >> 6, wr = wid >> 1, wc = wid & 1;
  int m0 = blockIdx.x*128;                 // c tile (0/1)
  int bh = blockIdx.y, b = bh >> 3, h = bh & 7;
  const unsigned short* At = attT + bh*16384;  // [e][d], ld 128
  f32x4 acc[4][4] = {};
  for (int k0 = 0; k0 < 128; k0 += 64){
    __syncthreads();
    stage128x64s(Wpbf, m0, C4, h*128 + k0, ldsA, tid);
    stage128x64s(At,   0,  128, k0, ldsB, tid);
    __syncthreads();
    mma_tiles<64,2,1,1>(ldsA, ldsB, acc, wr, wc, lane);
  }
  int colg = lane & 15, rowg = (lane >> 4) * 4;
#pragma unroll
  for (int mf = 0; mf < 4; ++mf)
#pragma unroll
    for (int nf = 0; nf < 4; ++nf)
#pragma unroll
      for (int r = 0; r < 4; ++r){
        int row = m0 + wr*64 + mf*16 + rowg + r;
        int col = wc*64 + nf*16 + colg;
        WpEff[b*(256*C4) + row*C4 + h*128 + col] = f2b(acc[mf][nf][r]);
      }
}

// ---------------- W2[b][c][j] = sum_c4 WpEff[b][c][c4] * WvT[j][c4] ----------------
__global__ __launch_bounds__(256) void k_gemm_w2(const unsigned short* __restrict__ WpEff,
                                                 const unsigned short* __restrict__ WvT,
                                                 unsigned short* __restrict__ W2){
  __shared__ __align__(16) unsigned short ldsA[128*64];
  __shared__ __align__(16) unsigned short ldsB[128*64];
  int tid = threadIdx.x, lane = tid & 63, wid = tid >> 6, wr = wid >> 1, wc = wid & 1;
  int m0 = blockIdx.x*128, n0 = blockIdx.y*128, b = blockIdx.z;
  const unsigned short* A = WpEff + b*(256*C4);
  f32x4 acc[4][4] = {};
  for (int k0 = 0; k0 < C4; k0 += 64){
    __syncthreads();
    stage128x64s(A,   m0, C4, k0, ldsA, tid);
    stage128x64s(WvT, n0, C4, k0, ldsB, tid);
    __syncthreads();
    mma_tiles<64,2,1,1>(ldsA, ldsB, acc, wr, wc, lane);
  }
  int colg = lane & 15, rowg = (lane >> 4) * 4;
#pragma unroll
  for (int mf = 0; mf < 4; ++mf)
#pragma unroll
    for (int nf = 0; nf < 4; ++nf)
#pragma unroll
      for (int r = 0; r < 4; ++r){
        int row = m0 + wr*64 + mf*16 + rowg + r;
        int col = n0 + wc*64 + nf*16 + colg;
        W2[b*65536 + row*256 + col] = f2b(acc[mf][nf][r]);
      }
}

// ---------------- out[b,n,c] = relu( sum_j x[b,n,j]*W2[b][c][j] + bp[c] ) ----------------
__global__ __launch_bounds__(256) void k_gemm_out(const unsigned short* __restrict__ xbf,
                                                  const unsigned short* __restrict__ W2,
                                                  const float* __restrict__ bp,
                                                  float* __restrict__ out){
  __shared__ __align__(16) unsigned short ldsA[2][8192];
  __shared__ __align__(16) unsigned short ldsB[2][8192];
  int tid = threadIdx.x, lane = tid & 63, wid = tid >> 6, wr = wid >> 1, wc = wid & 1;
  int m0 = blockIdx.x*128, n0 = blockIdx.y*128, b = blockIdx.z;
  const unsigned short* A = xbf + b*(NSEQ*256);
  const unsigned short* Bm = W2 + b*65536;
  f32x4 acc[4][4] = {};
  stage128x64s(A,  m0, 256, 0, ldsA[0], tid);
  stage128x64s(Bm, n0, 256, 0, ldsB[0], tid);
  for (int t = 0; t < 4; ++t){
    int cur = t & 1;
    if (t < 3){
      stage128x64s(A,  m0, 256, (t+1)*64, ldsA[cur^1], tid);
      stage128x64s(Bm, n0, 256, (t+1)*64, ldsB[cur^1], tid);
      WAITVM8();
    } else WAITVM0();
    barrier();
    mma_tiles<64,2,1,1>(ldsA[cur], ldsB[cur], acc, wr, wc, lane);
    WAITLGKM();
    barrier();
  }
  int colg = lane & 15, rowg = (lane >> 4) * 4;
#pragma unroll
  for (int mf = 0; mf < 4; ++mf)
#pragma unroll
    for (int nf = 0; nf < 4; ++nf){
      int col = n0 + wc*64 + nf*16 + colg;
      float bias = bp[col];
#pragma unroll
      for (int r = 0; r < 4; ++r){
        int row = m0 + wr*64 + mf*16 + rowg + r;
        out[(b*NSEQ + row)*256 + col] = fmaxf(acc[mf][nf][r] + bias, 0.f);
      }
    }
}

extern "C" void kernel_launch(void* const* d_in, const int* in_sizes, int n_in,
                              void* d_out, int out_size, void* d_ws, size_t ws_size,
                              hipStream_t stream){
  (void)in_sizes; (void)n_in; (void)out_size; (void)ws_size;
  const float* x  = (const float*)d_in[0];
  const float* Wq = (const float*)d_in[1];
  const float* Wk = (const float*)d_in[2];
  const float* Wv = (const float*)d_in[3];
  const float* Wp = (const float*)d_in[4];
  const float* bp = (const float*)d_in[5];
  float* out = (float*)d_out;
  char* ws = (char*)d_ws;

  unsigned short* Xq     = (unsigned short*)(ws + 0);          // 64 MB  [8][4096][1024] bf16
  unsigned short* Xk     = (unsigned short*)(ws + 67108864);   // 64 MB
  unsigned short* xbf    = (unsigned short*)(ws + 134217728);  // 16 MB  [32768][256] bf16
  unsigned short* zT     = (unsigned short*)(ws + 150994944);  // 16 MB  [16][128][4096] bf16
  unsigned short* basesT = (unsigned short*)(ws + 167772160);  // 4 MB   [16][128][1024] bf16
  unsigned short* WpEff  = (unsigned short*)(ws + 171966464);  // 4 MB   [8][256][1024] bf16
  unsigned short* attT   = (unsigned short*)(ws + 176160768);  // 2 MB   [64][128][128] bf16
  unsigned short* Wcat   = (unsigned short*)(ws + 178257920);  // 1 MB   [2048][256] bf16 (Wq;Wk)
  unsigned short* WvT    = (unsigned short*)(ws + 179306496);  // 0.5 MB [256][1024] bf16
  unsigned short* Wpbf   = (unsigned short*)(ws + 179830784);  // 0.5 MB [256][1024] bf16
  unsigned short* W2     = (unsigned short*)(ws + 180355072);  // 1 MB   [8][256][256] bf16
  float*          bRawP  = (float*)(ws + 181403648);           // 32 MB  [4][16][128][1024] f32
  unsigned*       pooled = (unsigned*)bRawP;                   // 8 MB, aliases bRawP slice 0 (dead at pool time)

  k_cast<<<8192, 256, 0, stream>>>(x,  xbf, 8388608);
  k_cast<<<256,  256, 0, stream>>>(Wq, Wcat,          262144);
  k_cast<<<256,  256, 0, stream>>>(Wk, Wcat + 262144, 262144);
  k_cast<<<256,  256, 0, stream>>>(Wp, Wpbf,          262144);
  k_transpose_wv<<<1024, 256, 0, stream>>>(Wv, WvT);

  (void)hipMemsetAsync(pooled, 0, (size_t)16*128*1024*4, stream);    // mapped -inf
  k_gemm_qk<<<dim3(256, 16), 256, 0, stream>>>(xbf, Wcat, Xq, Xk, pooled);
  k_norm<<<2048, 256, 0, stream>>>(bRawP, pooled, basesT, 0);

  for (int st = 0; st < 3; ++st){
    k_gemm_z<<<dim3(32, 16), 256, 0, stream>>>(Xq, Xk, basesT, zT);
    k_gemm_bases<<<dim3(8, 16, 4), 256, 0, stream>>>(Xq, Xk, zT, bRawP);
    k_norm<<<2048, 256, 0, stream>>>(bRawP, pooled, basesT, 4);
  }

  k_attn<<<64, 256, 0, stream>>>(basesT, attT);
  k_wpeff<<<dim3(2, 64), 256, 0, stream>>>(Wpbf, attT, WpEff);
  k_gemm_w2<<<dim3(2, 2, 8), 256, 0, stream>>>(WpEff, WvT, W2);
  k_gemm_out<<<dim3(32, 2, 8), 256, 0, stream>>>(xbf, W2, bp, out);
}

// Round 6
// 303.271 us; speedup vs baseline: 2.9941x; 1.3220x over previous
//
#include <hip/hip_runtime.h>
#include <hip/hip_bf16.h>

// Problem constants
#define NSEQ 4096
#define C4   1024
#define SCALE_F 0.17677669529663687f   // (256/8)^-0.5
#define SLC   524288                   // floats per PB/GT partial slice: 16*128*256

typedef __attribute__((ext_vector_type(8))) short bf16x8;
typedef __attribute__((ext_vector_type(4))) float f32x4;
typedef __attribute__((ext_vector_type(8))) unsigned short u16x8;
typedef __attribute__((ext_vector_type(4))) unsigned short u16x4;

__device__ __forceinline__ unsigned short f2b(float x){
  union{float f; unsigned u;} v; v.f = x;
  unsigned r = v.u + 0x7fffu + ((v.u>>16)&1u);
  return (unsigned short)(r>>16);
}
// monotone f32 <-> u32 mapping for atomicMax pooling
__device__ __forceinline__ unsigned mapf(float x){
  unsigned u = __float_as_uint(x);
  return (u & 0x80000000u) ? ~u : (u | 0x80000000u);
}
__device__ __forceinline__ float unmapf(unsigned m){
  unsigned u = (m & 0x80000000u) ? (m ^ 0x80000000u) : ~m;
  return __uint_as_float(u);
}

typedef __attribute__((address_space(1))) void* gas_p;
typedef __attribute__((address_space(3))) void* las_p;
#define GLDS16(gp, lp) __builtin_amdgcn_global_load_lds((gas_p)(gp), (las_p)(lp), 16, 0, 0)

#define WAITVM8() asm volatile("s_waitcnt vmcnt(8)" ::: "memory")
#define WAITVM4() asm volatile("s_waitcnt vmcnt(4)" ::: "memory")
#define WAITVM0() asm volatile("s_waitcnt vmcnt(0)" ::: "memory")
#define WAITLGKM() asm volatile("s_waitcnt lgkmcnt(0)" ::: "memory")
__device__ __forceinline__ void barrier(){
  asm volatile("" ::: "memory");
  __builtin_amdgcn_s_barrier();
  asm volatile("" ::: "memory");
}

// Stage a 128x64 bf16 tile, chunk-XOR swizzled: LDS slot (r,c8) holds global chunk (c8^(r&7)).
__device__ __forceinline__ void stage128x64s(const unsigned short* G, int row0, int ld, int k0,
                                             unsigned short* lds, int tid){
#pragma unroll
  for (int i = 0; i < 4; ++i){
    int cid = i*256 + tid;          // 1024 chunks of 16B
    int r = cid >> 3, c8 = cid & 7;
    GLDS16(G + (row0 + r)*ld + k0 + ((c8 ^ (r & 7))*8), lds + cid*8);
  }
}

// MFMA over staged tiles. D[m,n] += sum_k A[m,k]*B[n,k].
// Modes: 0=linear, 1=chunk-XOR (stage128x64s), 2=np-XOR (reg-transposed B).
template<int LD, int NK, int MA, int MB>
__device__ __forceinline__ void mma_tiles(const unsigned short* ldsA, const unsigned short* ldsB,
                                          f32x4 acc[4][4], int wr, int wc, int lane){
  const int rowg = lane & 15, q4 = lane >> 4;
#pragma unroll
  for (int kc = 0; kc < NK; ++kc){
    bf16x8 a[4], b[4];
#pragma unroll
    for (int mf = 0; mf < 4; ++mf){
      int row = wr*64 + mf*16 + rowg;
      int off;
      if constexpr (MA == 1) off = ((kc*4 + q4) ^ (row & 7)) * 8;
      else                   off = kc*32 + q4*8;
      a[mf] = *(const bf16x8*)(ldsA + row*LD + off);
    }
#pragma unroll
    for (int nf = 0; nf < 4; ++nf){
      int col = wc*64 + nf*16 + rowg;
      int off;
      if constexpr (MB == 1)      off = ((kc*4 + q4) ^ (col & 7)) * 8;
      else if constexpr (MB == 2) off = (kc*32 + q4*8) ^ ((((col>>3) ^ col) & 7) << 3);
      else                        off = kc*32 + q4*8;
      b[nf] = *(const bf16x8*)(ldsB + col*LD + off);
    }
#pragma unroll
    for (int mf = 0; mf < 4; ++mf)
#pragma unroll
      for (int nf = 0; nf < 4; ++nf)
        acc[mf][nf] = __builtin_amdgcn_mfma_f32_16x16x32_bf16(a[mf], b[nf], acc[mf][nf], 0, 0, 0);
  }
}

// ---------------- casts / transposes ----------------
__global__ __launch_bounds__(256) void k_cast(const float* __restrict__ src,
                                              unsigned short* __restrict__ dst, int n){
  int i = (blockIdx.x*256 + threadIdx.x) * 4;
  if (i < n){
    float4 v = *(const float4*)(src + i);
    u16x4 o = { f2b(v.x), f2b(v.y), f2b(v.z), f2b(v.w) };
    *(u16x4*)(dst + i) = o;
  }
}

// dst[j*dstLd + colOff + r] = bf16(src[r*256 + j]); src: [1024][256] f32
__global__ __launch_bounds__(256) void k_transpose_w(const float* __restrict__ src,
                                                     unsigned short* __restrict__ dst,
                                                     int dstLd, int colOff){
  int t = blockIdx.x*256 + threadIdx.x;      // 262144 threads
  int j = t & 255, r = t >> 8;
  dst[j*dstLd + colOff + r] = f2b(src[r*256 + j]);
}

// ---------------- q/k projection + fused adaptive-max-pool (NO X store) ----------------
__global__ __launch_bounds__(256) void k_gemm_qk(const unsigned short* __restrict__ xbf,
                                                 const unsigned short* __restrict__ Wcat,
                                                 unsigned* __restrict__ pooled){
  __shared__ __align__(16) unsigned short ldsA[128*64];
  __shared__ __align__(16) unsigned short ldsB[128*64];
  int tid = threadIdx.x, lane = tid & 63, wid = tid >> 6, wr = wid >> 1, wc = wid & 1;
  int m0 = blockIdx.x*128, n0 = blockIdx.y*128;
  f32x4 acc[4][4] = {};
  for (int k0 = 0; k0 < 256; k0 += 64){
    __syncthreads();
    stage128x64s(xbf,  m0, 256, k0, ldsA, tid);
    stage128x64s(Wcat, n0, 256, k0, ldsB, tid);
    __syncthreads();
    mma_tiles<64,2,1,1>(ldsA, ldsB, acc, wr, wc, lane);
  }
  int colg = lane & 15;
  int b = m0 >> 12, kbase = (m0 & 4095) >> 5;
  // fused pool: window = kbase + wr*2 (+1 for mf 2,3)
#pragma unroll
  for (int nf = 0; nf < 4; ++nf){
    float wlo = -3e38f, whi = -3e38f;
#pragma unroll
    for (int r = 0; r < 4; ++r){
      wlo = fmaxf(wlo, fmaxf(acc[0][nf][r], acc[1][nf][r]));
      whi = fmaxf(whi, fmaxf(acc[2][nf][r], acc[3][nf][r]));
    }
    wlo = fmaxf(wlo, __shfl_xor(wlo, 16)); wlo = fmaxf(wlo, __shfl_xor(wlo, 32));
    whi = fmaxf(whi, __shfl_xor(whi, 16)); whi = fmaxf(whi, __shfl_xor(whi, 32));
    if (lane < 16){
      int col = n0 + wc*64 + nf*16 + colg;
      int sbp = b + ((col >> 10) << 3);
      int c4 = col & 1023;
      atomicMax(&pooled[(sbp*128 + kbase + wr*2    )*C4 + c4], mapf(wlo));
      atomicMax(&pooled[(sbp*128 + kbase + wr*2 + 1)*C4 + c4], mapf(whi));
    }
  }
}

// ---------------- l2-normalize rows over c4 -> basesT bf16 ----------------
// S==0: decode mapped-u32 pooled; S==1: read f32 bRaw.
__global__ __launch_bounds__(256) void k_norm(const float* __restrict__ bRaw,
                                              const unsigned* __restrict__ pooled,
                                              unsigned short* __restrict__ basesT, int S){
  int row = blockIdx.x, tid = threadIdx.x, lane = tid & 63, wid = tid >> 6;
  float4 v;
  if (S == 0){
    uint4 u = *(const uint4*)(pooled + row*C4 + tid*4);
    v.x = unmapf(u.x); v.y = unmapf(u.y); v.z = unmapf(u.z); v.w = unmapf(u.w);
  } else {
    v = *(const float4*)(bRaw + row*C4 + tid*4);
  }
  float ss = v.x*v.x + v.y*v.y + v.z*v.z + v.w*v.w;
  __shared__ float red[5];
#pragma unroll
  for (int o = 32; o; o >>= 1) ss += __shfl_down(ss, o);
  if (lane == 0) red[wid] = ss;
  __syncthreads();
  if (tid == 0) red[4] = 1.f / (1e-6f + sqrtf(red[0] + red[1] + red[2] + red[3]));
  __syncthreads();
  float inv = red[4];
  u16x4 o4 = { f2b(v.x*inv), f2b(v.y*inv), f2b(v.z*inv), f2b(v.w*inv) };
  *(u16x4*)(basesT + row*C4 + tid*4) = o4;
}

// ---------------- PB partial: part[ks][sb][k][c] = sum_{c4 in ks} basesT[sb][k][c4]*WT[c][off+c4] ----------------
__global__ __launch_bounds__(256) void k_pb(const unsigned short* __restrict__ basesT,
                                            const unsigned short* __restrict__ WcatT,
                                            float* __restrict__ part){
  __shared__ __align__(16) unsigned short ldsA[128*64];
  __shared__ __align__(16) unsigned short ldsB[128*64];
  int tid = threadIdx.x, lane = tid & 63, wid = tid >> 6, wr = wid >> 1, wc = wid & 1;
  int n0 = blockIdx.x*128, sb = blockIdx.y, ks = blockIdx.z;
  const unsigned short* A = basesT + sb*(128*C4);
  int off = (sb >= 8) ? 1024 : 0;
  f32x4 acc[4][4] = {};
  for (int t = 0; t < 4; ++t){
    __syncthreads();
    stage128x64s(A,     0,  C4,   ks*256 + t*64, ldsA, tid);
    stage128x64s(WcatT, n0, 2048, off + ks*256 + t*64, ldsB, tid);
    __syncthreads();
    mma_tiles<64,2,1,1>(ldsA, ldsB, acc, wr, wc, lane);
  }
  int colg = lane & 15, rowg = (lane >> 4) * 4;
#pragma unroll
  for (int mf = 0; mf < 4; ++mf)
#pragma unroll
    for (int nf = 0; nf < 4; ++nf)
#pragma unroll
      for (int r = 0; r < 4; ++r)
        part[ks*SLC + (sb*128 + wr*64 + mf*16 + rowg + r)*256 + n0 + wc*64 + nf*16 + colg]
          = acc[mf][nf][r];
}

// ---------------- reduce S partial slices -> bf16 ----------------
__global__ __launch_bounds__(256) void k_redgt(const float* __restrict__ src,
                                               unsigned short* __restrict__ dst, int S){
  int i = (blockIdx.x*256 + threadIdx.x) * 4;   // over SLC
  float4 a = {0.f,0.f,0.f,0.f};
  for (int s = 0; s < S; ++s){
    float4 u = *(const float4*)(src + s*SLC + i);
    a.x += u.x; a.y += u.y; a.z += u.z; a.w += u.w;
  }
  u16x4 o = { f2b(a.x), f2b(a.y), f2b(a.z), f2b(a.w) };
  *(u16x4*)(dst + i) = o;
}

// ---------------- z-step: scores[n,k] = x[n,:].PBT[k,:]; softmax over k (in regs); store zT[k][n] ----------------
__global__ __launch_bounds__(256) void k_gemm_z(const unsigned short* __restrict__ xbf,
                                                const unsigned short* __restrict__ PBT,
                                                unsigned short* __restrict__ zT){
  __shared__ __align__(16) unsigned short smem[32768];
  __shared__ float redb[2][2][128];
  unsigned short* zt = smem;
  int tid = threadIdx.x, lane = tid & 63, wid = tid >> 6, wr = wid >> 1, wc = wid & 1;
  int m0 = blockIdx.x*128, sb = blockIdx.y;
  const unsigned short* A = xbf + (sb & 7)*(NSEQ*256);
  const unsigned short* B = PBT + sb*(128*256);
  f32x4 acc[4][4] = {};
  stage128x64s(A, m0, 256, 0, smem, tid);
  stage128x64s(B, 0,  256, 0, smem + 16384, tid);
  for (int t = 0; t < 4; ++t){
    int cur = t & 1;
    if (t < 3){
      stage128x64s(A, m0, 256, (t+1)*64, smem + (cur^1)*8192, tid);
      stage128x64s(B, 0,  256, (t+1)*64, smem + 16384 + (cur^1)*8192, tid);
      WAITVM8();
    } else WAITVM0();
    barrier();
    mma_tiles<64,2,1,1>(smem + cur*8192, smem + 16384 + cur*8192, acc, wr, wc, lane);
    WAITLGKM();
    barrier();
  }
  int colg = lane & 15, rowg = (lane >> 4) * 4;
  float sm[4][4];
#pragma unroll
  for (int mf = 0; mf < 4; ++mf)
#pragma unroll
    for (int r = 0; r < 4; ++r){
      float m = fmaxf(fmaxf(acc[mf][0][r], acc[mf][1][r]), fmaxf(acc[mf][2][r], acc[mf][3][r]));
#pragma unroll
      for (int o = 1; o < 16; o <<= 1) m = fmaxf(m, __shfl_xor(m, o));
      if (colg == 0) redb[0][wc][wr*64 + mf*16 + rowg + r] = m;
    }
  barrier();
#pragma unroll
  for (int mf = 0; mf < 4; ++mf)
#pragma unroll
    for (int r = 0; r < 4; ++r){
      int idx = wr*64 + mf*16 + rowg + r;
      float m = fmaxf(redb[0][0][idx], redb[0][1][idx]);
      float s = 0.f;
#pragma unroll
      for (int nf = 0; nf < 4; ++nf){
        float e = __expf(acc[mf][nf][r] - m);
        acc[mf][nf][r] = e; s += e;
      }
#pragma unroll
      for (int o = 1; o < 16; o <<= 1) s += __shfl_xor(s, o);
      if (colg == 0) redb[1][wc][idx] = s;
    }
  barrier();
#pragma unroll
  for (int mf = 0; mf < 4; ++mf)
#pragma unroll
    for (int r = 0; r < 4; ++r){
      int idx = wr*64 + mf*16 + rowg + r;
      sm[mf][r] = 1.f / (redb[1][0][idx] + redb[1][1][idx]);
    }
#pragma unroll
  for (int mf = 0; mf < 4; ++mf)
#pragma unroll
    for (int nf = 0; nf < 4; ++nf){
      int k = wc*64 + nf*16 + colg;
      int swz = (k & 7) << 3;
#pragma unroll
      for (int r = 0; r < 4; ++r){
        int n = wr*64 + mf*16 + rowg + r;
        zt[k*128 + (n ^ swz)] = f2b(acc[mf][nf][r] * sm[mf][r]);
      }
    }
  WAITLGKM();
  barrier();
#pragma unroll
  for (int i = 0; i < 8; ++i){
    int cid = i*256 + tid;
    int kk = cid >> 4, j8 = cid & 15;
    int nbase = (j8*8) ^ ((kk & 7) << 3);
    *(uint4*)(zT + sb*(128*NSEQ) + kk*NSEQ + m0 + nbase) = *(const uint4*)(zt + kk*128 + j8*8);
  }
}

// ---------------- GT partial: part[ks][sb][k][c] = sum_{n in ks} zT[k,n]*x[n,c] ----------------
__global__ __launch_bounds__(256) void k_gemm_gt(const unsigned short* __restrict__ xbf,
                                                 const unsigned short* __restrict__ zT,
                                                 float* __restrict__ part){
  __shared__ __align__(16) unsigned short ldsA[2][8192];
  __shared__ __align__(16) unsigned short ldsB[2][8192];   // x^T: [128 c][64 n], np-XOR swizzled
  int tid = threadIdx.x, lane = tid & 63, wid = tid >> 6, wr = wid >> 1, wc = wid & 1;
  int c0 = blockIdx.x*128, sb = blockIdx.y, ks = blockIdx.z;
  const unsigned short* xb = xbf + (sb & 7)*(NSEQ*256);
  const unsigned short* Zt = zT + sb*(128*NSEQ);
  int base = ks*512;
  f32x4 acc[4][4] = {};
  u16x8 vB[4];
  int np_[4], c8_[4];
#pragma unroll
  for (int i = 0; i < 4; ++i){
    int cid = i*256 + tid;
    np_[i] = cid >> 4; c8_[i] = cid & 15;
  }
  stage128x64s(Zt, 0, NSEQ, base, ldsA[0], tid);
#pragma unroll
  for (int i = 0; i < 4; ++i)
    vB[i] = *(const u16x8*)(xb + (base + np_[i])*256 + c0 + c8_[i]*8);
  for (int t = 0; t < 8; ++t){
    int cur = t & 1, n0 = base + t*64;
    if (t < 7){
      stage128x64s(Zt, 0, NSEQ, n0 + 64, ldsA[cur^1], tid);
      WAITVM4();
    } else WAITVM0();
#pragma unroll
    for (int i = 0; i < 4; ++i){
#pragma unroll
      for (int j = 0; j < 8; ++j)
        ldsB[cur][(c8_[i]*8 + j)*64 + (np_[i] ^ (((c8_[i] ^ j) & 7) << 3))] = vB[i][j];
    }
    WAITLGKM();
    barrier();
    if (t < 7){
#pragma unroll
      for (int i = 0; i < 4; ++i)
        vB[i] = *(const u16x8*)(xb + (n0 + 64 + np_[i])*256 + c0 + c8_[i]*8);
    }
    mma_tiles<64,2,1,2>(ldsA[cur], ldsB[cur], acc, wr, wc, lane);
    WAITLGKM();
    barrier();
  }
  int colg = lane & 15, rowg = (lane >> 4) * 4;
#pragma unroll
  for (int mf = 0; mf < 4; ++mf)
#pragma unroll
    for (int nf = 0; nf < 4; ++nf)
#pragma unroll
      for (int r = 0; r < 4; ++r)
        part[ks*SLC + (sb*128 + wr*64 + mf*16 + rowg + r)*256 + c0 + wc*64 + nf*16 + colg]
          = acc[mf][nf][r];
}

// ---------------- bases_new raw: bRaw[sb][k][c4] = sum_c W[c4,c]*GT[k,c] ----------------
__global__ __launch_bounds__(256) void k_pbases(const unsigned short* __restrict__ Wcat,
                                                const unsigned short* __restrict__ GTbf,
                                                float* __restrict__ bRaw){
  __shared__ __align__(16) unsigned short ldsA[128*64];
  __shared__ __align__(16) unsigned short ldsB[128*64];
  int tid = threadIdx.x, lane = tid & 63, wid = tid >> 6, wr = wid >> 1, wc = wid & 1;
  int m0 = blockIdx.x*128, sb = blockIdx.y;
  const unsigned short* A = Wcat + ((sb >= 8) ? 1024*256 : 0);
  const unsigned short* B = GTbf + sb*(128*256);
  f32x4 acc[4][4] = {};
  for (int t = 0; t < 4; ++t){
    __syncthreads();
    stage128x64s(A, m0, 256, t*64, ldsA, tid);
    stage128x64s(B, 0,  256, t*64, ldsB, tid);
    __syncthreads();
    mma_tiles<64,2,1,1>(ldsA, ldsB, acc, wr, wc, lane);
  }
  int colg = lane & 15, rowg = (lane >> 4) * 4;
#pragma unroll
  for (int mf = 0; mf < 4; ++mf)
#pragma unroll
    for (int nf = 0; nf < 4; ++nf)
#pragma unroll
      for (int r = 0; r < 4; ++r){
        int c4 = m0 + wr*64 + mf*16 + rowg + r;
        int k  = wc*64 + nf*16 + colg;
        bRaw[(sb*128 + k)*C4 + c4] = acc[mf][nf][r];
      }
}

// ---------------- att per (b,h): softmax_e(SCALE * qh.kh) ; store attT[e][d] ----------------
__global__ __launch_bounds__(256) void k_attn(const unsigned short* __restrict__ basesT,
                                              unsigned short* __restrict__ attT){
  __shared__ __align__(16) char smem[98816];
  unsigned short* Qlt = (unsigned short*)smem;             // [128 d][128 k]
  unsigned short* Klt = (unsigned short*)(smem + 32768);   // [128 e][128 k]
  float* scores       = (float*)smem;                      // [128][129], aliases operands (post-MMA)
  unsigned short* at  = (unsigned short*)(smem + 66048);   // [128 e][128 d]
  int tid = threadIdx.x, lane = tid & 63, wid = tid >> 6, wr = wid >> 1, wc = wid & 1;
  int b = blockIdx.x >> 3, h = blockIdx.x & 7;
  const unsigned short* Q = basesT + b*(128*C4) + h*128;
  const unsigned short* K = basesT + (8 + b)*(128*C4) + h*128;
#pragma unroll
  for (int i = 0; i < 8; ++i){
    int cid = i*256 + tid, kk = cid >> 4, c8 = cid & 15;
    u16x8 vq = *(const u16x8*)(Q + kk*C4 + c8*8);
    u16x8 vk = *(const u16x8*)(K + kk*C4 + c8*8);
#pragma unroll
    for (int j = 0; j < 8; ++j){
      Qlt[(c8*8 + j)*128 + kk] = vq[j];
      Klt[(c8*8 + j)*128 + kk] = vk[j];
    }
  }
  __syncthreads();
  f32x4 acc[4][4] = {};
  mma_tiles<128,4,0,0>(Qlt, Klt, acc, wr, wc, lane);
  __syncthreads();
  int colg = lane & 15, rowg = (lane >> 4) * 4;
#pragma unroll
  for (int mf = 0; mf < 4; ++mf)
#pragma unroll
    for (int nf = 0; nf < 4; ++nf)
#pragma unroll
      for (int r = 0; r < 4; ++r)
        scores[(wr*64 + mf*16 + rowg + r)*129 + wc*64 + nf*16 + colg] = acc[mf][nf][r] * SCALE_F;
  __syncthreads();
  if (tid < 128){
    float mx = -3e38f;
    for (int j = 0; j < 128; ++j) mx = fmaxf(mx, scores[tid*129 + j]);
    float s = 0.f;
    for (int j = 0; j < 128; ++j){ float e = __expf(scores[tid*129 + j] - mx); scores[tid*129 + j] = e; s += e; }
    float inv = 1.f / s;
    for (int j = 0; j < 128; ++j) at[j*128 + tid] = f2b(scores[tid*129 + j] * inv);
  }
  __syncthreads();
#pragma unroll
  for (int i = 0; i < 8; ++i){
    int cid = i*256 + tid;
    *(uint4*)(attT + blockIdx.x*16384 + cid*8) = *(const uint4*)(at + cid*8);
  }
}

// ---------------- WpEff[b][c][h*128+e] = sum_d Wp[c,h*128+d] * att[d,e] ----------------
__global__ __launch_bounds__(256) void k_wpeff(const unsigned short* __restrict__ Wpbf,
                                               const unsigned short* __restrict__ attT,
                                               unsigned short* __restrict__ WpEff){
  __shared__ __align__(16) unsigned short ldsA[128*64];
  __shared__ __align__(16) unsigned short ldsB[128*64];
  int tid = threadIdx.x, lane = tid & 63, wid = tid >> 6, wr = wid >> 1, wc = wid & 1;
  int m0 = blockIdx.x*128;
  int bh = blockIdx.y, b = bh >> 3, h = bh & 7;
  const unsigned short* At = attT + bh*16384;
  f32x4 acc[4][4] = {};
  for (int k0 = 0; k0 < 128; k0 += 64){
    __syncthreads();
    stage128x64s(Wpbf, m0, C4, h*128 + k0, ldsA, tid);
    stage128x64s(At,   0,  128, k0, ldsB, tid);
    __syncthreads();
    mma_tiles<64,2,1,1>(ldsA, ldsB, acc, wr, wc, lane);
  }
  int colg = lane & 15, rowg = (lane >> 4) * 4;
#pragma unroll
  for (int mf = 0; mf < 4; ++mf)
#pragma unroll
    for (int nf = 0; nf < 4; ++nf)
#pragma unroll
      for (int r = 0; r < 4; ++r){
        int row = m0 + wr*64 + mf*16 + rowg + r;
        int col = wc*64 + nf*16 + colg;
        WpEff[b*(256*C4) + row*C4 + h*128 + col] = f2b(acc[mf][nf][r]);
      }
}

// ---------------- W2[b][c][j] = sum_c4 WpEff[b][c][c4] * WvT[j][c4] ----------------
__global__ __launch_bounds__(256) void k_gemm_w2(const unsigned short* __restrict__ WpEff,
                                                 const unsigned short* __restrict__ WvT,
                                                 unsigned short* __restrict__ W2){
  __shared__ __align__(16) unsigned short ldsA[128*64];
  __shared__ __align__(16) unsigned short ldsB[128*64];
  int tid = threadIdx.x, lane = tid & 63, wid = tid >> 6, wr = wid >> 1, wc = wid & 1;
  int m0 = blockIdx.x*128, n0 = blockIdx.y*128, b = blockIdx.z;
  const unsigned short* A = WpEff + b*(256*C4);
  f32x4 acc[4][4] = {};
  for (int k0 = 0; k0 < C4; k0 += 64){
    __syncthreads();
    stage128x64s(A,   m0, C4, k0, ldsA, tid);
    stage128x64s(WvT, n0, C4, k0, ldsB, tid);
    __syncthreads();
    mma_tiles<64,2,1,1>(ldsA, ldsB, acc, wr, wc, lane);
  }
  int colg = lane & 15, rowg = (lane >> 4) * 4;
#pragma unroll
  for (int mf = 0; mf < 4; ++mf)
#pragma unroll
    for (int nf = 0; nf < 4; ++nf)
#pragma unroll
      for (int r = 0; r < 4; ++r){
        int row = m0 + wr*64 + mf*16 + rowg + r;
        int col = n0 + wc*64 + nf*16 + colg;
        W2[b*65536 + row*256 + col] = f2b(acc[mf][nf][r]);
      }
}

// ---------------- out[b,n,c] = relu( sum_j x[b,n,j]*W2[b][c][j] + bp[c] ) ----------------
__global__ __launch_bounds__(256) void k_gemm_out(const unsigned short* __restrict__ xbf,
                                                  const unsigned short* __restrict__ W2,
                                                  const float* __restrict__ bp,
                                                  float* __restrict__ out){
  __shared__ __align__(16) unsigned short ldsA[2][8192];
  __shared__ __align__(16) unsigned short ldsB[2][8192];
  int tid = threadIdx.x, lane = tid & 63, wid = tid >> 6, wr = wid >> 1, wc = wid & 1;
  int m0 = blockIdx.x*128, n0 = blockIdx.y*128, b = blockIdx.z;
  const unsigned short* A = xbf + b*(NSEQ*256);
  const unsigned short* Bm = W2 + b*65536;
  f32x4 acc[4][4] = {};
  stage128x64s(A,  m0, 256, 0, ldsA[0], tid);
  stage128x64s(Bm, n0, 256, 0, ldsB[0], tid);
  for (int t = 0; t < 4; ++t){
    int cur = t & 1;
    if (t < 3){
      stage128x64s(A,  m0, 256, (t+1)*64, ldsA[cur^1], tid);
      stage128x64s(Bm, n0, 256, (t+1)*64, ldsB[cur^1], tid);
      WAITVM8();
    } else WAITVM0();
    barrier();
    mma_tiles<64,2,1,1>(ldsA[cur], ldsB[cur], acc, wr, wc, lane);
    WAITLGKM();
    barrier();
  }
  int colg = lane & 15, rowg = (lane >> 4) * 4;
#pragma unroll
  for (int mf = 0; mf < 4; ++mf)
#pragma unroll
    for (int nf = 0; nf < 4; ++nf){
      int col = n0 + wc*64 + nf*16 + colg;
      float bias = bp[col];
#pragma unroll
      for (int r = 0; r < 4; ++r){
        int row = m0 + wr*64 + mf*16 + rowg + r;
        out[(b*NSEQ + row)*256 + col] = fmaxf(acc[mf][nf][r] + bias, 0.f);
      }
    }
}

extern "C" void kernel_launch(void* const* d_in, const int* in_sizes, int n_in,
                              void* d_out, int out_size, void* d_ws, size_t ws_size,
                              hipStream_t stream){
  (void)in_sizes; (void)n_in; (void)out_size; (void)ws_size;
  const float* x  = (const float*)d_in[0];
  const float* Wq = (const float*)d_in[1];
  const float* Wk = (const float*)d_in[2];
  const float* Wv = (const float*)d_in[3];
  const float* Wp = (const float*)d_in[4];
  const float* bp = (const float*)d_in[5];
  float* out = (float*)d_out;
  char* ws = (char*)d_ws;

  unsigned short* xbf    = (unsigned short*)(ws + 0);          // 16 MB [8][4096][256] bf16
  unsigned short* zT     = (unsigned short*)(ws + 16777216);   // 32 MB [16][128][4096] bf16
  float*          bPart  = (float*)(ws + 50331648);            // 16 MB [8][16][128][256] f32
  float*          bRawP  = (float*)(ws + 67108864);            // 8 MB  [16][128][1024] f32
  unsigned*       pooled = (unsigned*)(ws + 75497472);         // 8 MB  [16][128][1024] u32
  unsigned short* basesT = (unsigned short*)(ws + 83886080);   // 4 MB  [16][128][1024] bf16
  unsigned short* PBT    = (unsigned short*)(ws + 88080384);   // 1 MB  [16][128][256] bf16
  unsigned short* GTbf   = (unsigned short*)(ws + 89128960);   // 1 MB  [16][128][256] bf16
  unsigned short* Wcat   = (unsigned short*)(ws + 90177536);   // 1 MB  [2048][256] bf16 (Wq;Wk)
  unsigned short* WcatT  = (unsigned short*)(ws + 91226112);   // 1 MB  [256][2048] bf16 (WqT|WkT)
  unsigned short* WvT    = (unsigned short*)(ws + 92274688);   // 0.5MB [256][1024] bf16
  unsigned short* Wpbf   = (unsigned short*)(ws + 92798976);   // 0.5MB [256][1024] bf16
  unsigned short* WpEff  = (unsigned short*)(ws + 93323264);   // 4 MB  [8][256][1024] bf16
  unsigned short* attT   = (unsigned short*)(ws + 97517568);   // 2 MB  [64][128][128] bf16
  unsigned short* W2     = (unsigned short*)(ws + 99614720);   // 1 MB  [8][256][256] bf16

  k_cast<<<8192, 256, 0, stream>>>(x,  xbf, 8388608);
  k_cast<<<256,  256, 0, stream>>>(Wq, Wcat,          262144);
  k_cast<<<256,  256, 0, stream>>>(Wk, Wcat + 262144, 262144);
  k_cast<<<256,  256, 0, stream>>>(Wp, Wpbf,          262144);
  k_transpose_w<<<1024, 256, 0, stream>>>(Wv, WvT,   1024, 0);
  k_transpose_w<<<1024, 256, 0, stream>>>(Wq, WcatT, 2048, 0);
  k_transpose_w<<<1024, 256, 0, stream>>>(Wk, WcatT, 2048, 1024);

  (void)hipMemsetAsync(pooled, 0, (size_t)16*128*1024*4, stream);    // mapped -inf
  k_gemm_qk<<<dim3(256, 16), 256, 0, stream>>>(xbf, Wcat, pooled);
  k_norm<<<2048, 256, 0, stream>>>(bRawP, pooled, basesT, 0);

  for (int st = 0; st < 3; ++st){
    k_pb<<<dim3(2, 16, 4), 256, 0, stream>>>(basesT, WcatT, bPart);
    k_redgt<<<512, 256, 0, stream>>>(bPart, PBT, 4);
    k_gemm_z<<<dim3(32, 16), 256, 0, stream>>>(xbf, PBT, zT);
    k_gemm_gt<<<dim3(2, 16, 8), 256, 0, stream>>>(xbf, zT, bPart);
    k_redgt<<<512, 256, 0, stream>>>(bPart, GTbf, 8);
    k_pbases<<<dim3(8, 16), 256, 0, stream>>>(Wcat, GTbf, bRawP);
    k_norm<<<2048, 256, 0, stream>>>(bRawP, pooled, basesT, 1);
  }

  k_attn<<<64, 256, 0, stream>>>(basesT, attT);
  k_wpeff<<<dim3(2, 64), 256, 0, stream>>>(Wpbf, attT, WpEff);
  k_gemm_w2<<<dim3(2, 2, 8), 256, 0, stream>>>(WpEff, WvT, W2);
  k_gemm_out<<<dim3(32, 2, 8), 256, 0, stream>>>(xbf, W2, bp, out);
}